// Round 1
// baseline (3351.146 us; speedup 1.0000x reference)
//
#include <hip/hip_runtime.h>
#include <math.h>

// Problem constants
#define LSEQ   4096       // H*W
#define BSZ    4
#define DMODEL 256
#define DINNER 512
#define NROWS  16384      // B*L

__device__ __forceinline__ float silu_f(float v){ return v / (1.f + __expf(-v)); }
__device__ __forceinline__ float softplus_f(float v){
  return v > 0.f ? v + log1pf(__expf(-v)) : log1pf(__expf(v));
}

// ---------------- LayerNorm over channel dim ----------------
// x: (B, C=256, L) ; out xn: (B*L, 256)
__global__ __launch_bounds__(256) void ln_kernel(const float* __restrict__ x,
    const float* __restrict__ w, const float* __restrict__ bias,
    float* __restrict__ xn)
{
  int i = blockIdx.x;            // row = b*4096 + l
  int b = i >> 12, l = i & 4095;
  int c = threadIdx.x;
  float v = x[((size_t)(b*DMODEL + c) << 12) + l];
  __shared__ float s1[256], s2[256];
  s1[c] = v; s2[c] = v*v;
  __syncthreads();
  for (int off = 128; off > 0; off >>= 1){
    if (c < off){ s1[c] += s1[c+off]; s2[c] += s2[c+off]; }
    __syncthreads();
  }
  float mu  = s1[0] * (1.f/256.f);
  float var = s2[0] * (1.f/256.f) - mu*mu;
  float rs  = rsqrtf(var + 1e-5f);
  xn[(size_t)i*DMODEL + c] = (v - mu) * rs * w[c] + bias[c];
}

// ---------------- Generic tiled f32 GEMM: C = A @ W^T ----------------
// A: (M, lda) row-major (uses cols 0..K-1), W: (N, K) row-major, K = KT*16
// MODE 0: split write xin/z at col 512
// MODE 1: plain write, stride 48, guard n < N (N=48)
// MODE 2: + skip_scale * x_transposed  (out_proj)
// MODE 3: + bias, transposed store to (B, C, L)  (final proj)
// MODE 4: softplus(v + bias)  (dt_proj)
template<int MODE, int KT>
__global__ __launch_bounds__(256) void gemm_bt(
    const float* __restrict__ A, int lda,
    const float* __restrict__ W, int N,
    float* __restrict__ O1, float* __restrict__ O2,
    const float* __restrict__ bias,
    const float* __restrict__ xsrc,
    const float* __restrict__ sscale)
{
  __shared__ float As[16][68];   // [k][m], stride 68 floats (16B-aligned rows)
  __shared__ float Bs[16][68];
  const int tid = threadIdx.x;
  const int tx = tid & 15, ty = tid >> 4;
  const int mb = blockIdx.y * 64, nb = blockIdx.x * 64;
  const int lrow = tid >> 2;       // 0..63
  const int kq = (tid & 3) << 2;   // 0,4,8,12
  float acc[4][4] = {};

  for (int kt = 0; kt < KT; ++kt){
    const int k0 = kt << 4;
    float4 av = *(const float4*)(A + (size_t)(mb + lrow)*lda + k0 + kq);
    float4 bv = make_float4(0.f, 0.f, 0.f, 0.f);
    const int wrow = nb + lrow;
    if (MODE != 1 || wrow < N)
      bv = *(const float4*)(W + (size_t)wrow*(KT*16) + k0 + kq);
    __syncthreads();
    As[kq+0][lrow] = av.x; As[kq+1][lrow] = av.y; As[kq+2][lrow] = av.z; As[kq+3][lrow] = av.w;
    Bs[kq+0][lrow] = bv.x; Bs[kq+1][lrow] = bv.y; Bs[kq+2][lrow] = bv.z; Bs[kq+3][lrow] = bv.w;
    __syncthreads();
    #pragma unroll
    for (int k = 0; k < 16; ++k){
      float4 a = *(const float4*)&As[k][ty << 2];
      float4 b = *(const float4*)&Bs[k][tx << 2];
      acc[0][0] = fmaf(a.x, b.x, acc[0][0]); acc[0][1] = fmaf(a.x, b.y, acc[0][1]);
      acc[0][2] = fmaf(a.x, b.z, acc[0][2]); acc[0][3] = fmaf(a.x, b.w, acc[0][3]);
      acc[1][0] = fmaf(a.y, b.x, acc[1][0]); acc[1][1] = fmaf(a.y, b.y, acc[1][1]);
      acc[1][2] = fmaf(a.y, b.z, acc[1][2]); acc[1][3] = fmaf(a.y, b.w, acc[1][3]);
      acc[2][0] = fmaf(a.z, b.x, acc[2][0]); acc[2][1] = fmaf(a.z, b.y, acc[2][1]);
      acc[2][2] = fmaf(a.z, b.z, acc[2][2]); acc[2][3] = fmaf(a.z, b.w, acc[2][3]);
      acc[3][0] = fmaf(a.w, b.x, acc[3][0]); acc[3][1] = fmaf(a.w, b.y, acc[3][1]);
      acc[3][2] = fmaf(a.w, b.z, acc[3][2]); acc[3][3] = fmaf(a.w, b.w, acc[3][3]);
    }
  }

  #pragma unroll
  for (int i2 = 0; i2 < 4; ++i2){
    int mg = mb + (ty << 2) + i2;
    #pragma unroll
    for (int j = 0; j < 4; ++j){
      int ng = nb + (tx << 2) + j;
      float v = acc[i2][j];
      if (MODE == 0){
        if (ng < DINNER) O1[(size_t)mg*DINNER + ng] = v;
        else             O2[(size_t)mg*DINNER + (ng - DINNER)] = v;
      } else if (MODE == 1){
        if (ng < N) O1[(size_t)mg*48 + ng] = v;
      } else if (MODE == 2){
        int b = mg >> 12, l = mg & 4095;
        O1[(size_t)mg*DMODEL + ng] =
            v + sscale[0] * xsrc[((size_t)(b*DMODEL + ng) << 12) + l];
      } else if (MODE == 3){
        int b = mg >> 12, l = mg & 4095;
        O1[((size_t)(b*DMODEL + ng) << 12) + l] = v + bias[ng];
      } else { // MODE 4
        O1[(size_t)mg*DINNER + ng] = softplus_f(v + bias[ng]);
      }
    }
  }
}

// ---------------- Causal depthwise conv (width 4) + SiLU ----------------
// xin: (B*L, 512) ; xc: (B*L, 512)
__global__ __launch_bounds__(256) void conv_silu(const float* __restrict__ xin,
    const float* __restrict__ w, const float* __restrict__ cb,
    float* __restrict__ xc)
{
  int idx = blockIdx.x * 256 + threadIdx.x;  // over 16384*512
  int d = idx & 511;
  int i = idx >> 9;          // b*4096 + l
  int l = i & 4095;
  float acc = cb[d];
  #pragma unroll
  for (int j = 0; j < 4; ++j){
    int ls = l - 3 + j;
    if (ls >= 0) acc = fmaf(w[(d << 2) + j], xin[(size_t)(i - 3 + j)*512 + d], acc);
  }
  xc[idx] = silu_f(acc);
}

// ---------------- Selective scan ----------------
// One wave handles 4 channels (lane = 16*d_sub + n). Sequential over t.
__global__ __launch_bounds__(256) void scan_kernel(
    const float* __restrict__ u,     // xc (B*L,512)
    const float* __restrict__ dt,    // (B*L,512)
    const float* __restrict__ dbl,   // (B*L,48): [0:16)=dt_in, [16:32)=B, [32:48)=C
    const float* __restrict__ A_log, // (512,16)
    const float* __restrict__ Dp,    // (512)
    const float* __restrict__ z,     // (B*L,512)
    float* __restrict__ y)           // (B*L,512)
{
  int wave = (blockIdx.x * 256 + threadIdx.x) >> 6;  // 0..511
  int lane = threadIdx.x & 63;
  int b  = wave >> 7;         // 128 waves per batch
  int dg = wave & 127;
  int d  = dg * 4 + (lane >> 4);
  int n  = lane & 15;
  float Acoef = -__expf(A_log[d*16 + n]);
  float Dv = Dp[d];
  float h = 0.f;
  size_t base = (size_t)b * LSEQ;
  #pragma unroll 4
  for (int t = 0; t < LSEQ; ++t){
    size_t row = base + t;
    float dtv = dt[row*512 + d];
    float uv  = u[row*512 + d];
    float Bv  = dbl[row*48 + 16 + n];
    float Cv  = dbl[row*48 + 32 + n];
    float dA  = __expf(dtv * Acoef);
    h = fmaf(h, dA, dtv * uv * Bv);
    float py = h * Cv;
    py += __shfl_xor(py, 1);
    py += __shfl_xor(py, 2);
    py += __shfl_xor(py, 4);
    py += __shfl_xor(py, 8);
    if (n == 0){
      float zv = z[row*512 + d];
      y[row*512 + d] = (py + uv * Dv) * silu_f(zv);
    }
  }
}

extern "C" void kernel_launch(void* const* d_in, const int* in_sizes, int n_in,
                              void* d_out, int out_size, void* d_ws, size_t ws_size,
                              hipStream_t stream)
{
  const float* x          = (const float*)d_in[0];   // (4,256,64,64)
  const float* norm_w     = (const float*)d_in[1];
  const float* norm_b     = (const float*)d_in[2];
  const float* in_proj_w  = (const float*)d_in[3];   // (1024,256)
  const float* conv_w     = (const float*)d_in[4];   // (512,1,4)
  const float* conv_b     = (const float*)d_in[5];
  const float* x_proj_w   = (const float*)d_in[6];   // (48,512)
  const float* dt_proj_w  = (const float*)d_in[7];   // (512,16)
  const float* dt_proj_b  = (const float*)d_in[8];
  const float* A_log      = (const float*)d_in[9];   // (512,16)
  const float* D_ssm      = (const float*)d_in[10];
  const float* out_proj_w = (const float*)d_in[11];  // (256,512)
  const float* proj_w     = (const float*)d_in[12];  // (256,256)
  const float* proj_b     = (const float*)d_in[13];
  const float* skip_scale = (const float*)d_in[14];
  float* out = (float*)d_out;

  char* ws = (char*)d_ws;
  float* xn  = (float*)(ws);                        // 16 MB  [0,16)
  float* xin = (float*)(ws + ((size_t)16 << 20));   // 32 MB  [16,48)
  float* zb  = (float*)(ws + ((size_t)48 << 20));   // 32 MB  [48,80)
  float* xc  = (float*)(ws + ((size_t)80 << 20));   // 32 MB  [80,112)
  float* dbl = (float*)(ws + ((size_t)112 << 20));  //  3 MB  [112,115)
  float* dtb = (float*)(ws + ((size_t)115 << 20));  // 32 MB  [115,147)
  float* yb  = (float*)(ws + ((size_t)16 << 20));   // reuse xin slot
  float* xm  = (float*)(ws);                        // reuse xn slot

  // 1) LayerNorm
  ln_kernel<<<NROWS, 256, 0, stream>>>(x, norm_w, norm_b, xn);

  // 2) in_proj: (16384,256)@(256->1024), split into xin / z
  gemm_bt<0, 16><<<dim3(16, 256), 256, 0, stream>>>(
      xn, 256, in_proj_w, 1024, xin, zb, nullptr, nullptr, nullptr);

  // 3) causal conv + SiLU
  conv_silu<<<(NROWS * DINNER) / 256, 256, 0, stream>>>(xin, conv_w, conv_b, xc);

  // 4) x_proj: (16384,512)@(512->48)
  gemm_bt<1, 32><<<dim3(1, 256), 256, 0, stream>>>(
      xc, 512, x_proj_w, 48, dbl, nullptr, nullptr, nullptr, nullptr);

  // 5) dt_proj + softplus: (16384,16)@(16->512), A = dbl cols 0..15 (lda=48)
  gemm_bt<4, 1><<<dim3(8, 256), 256, 0, stream>>>(
      dbl, 48, dt_proj_w, 512, dtb, nullptr, dt_proj_b, nullptr, nullptr);

  // 6) selective scan + u*D + SiLU(z) gate
  scan_kernel<<<128, 256, 0, stream>>>(xc, dtb, dbl, A_log, D_ssm, zb, yb);

  // 7) out_proj + skip: (16384,512)@(512->256)
  gemm_bt<2, 32><<<dim3(4, 256), 256, 0, stream>>>(
      yb, 512, out_proj_w, 256, xm, nullptr, nullptr, x, skip_scale);

  // 8) final proj + bias, transposed store
  gemm_bt<3, 16><<<dim3(4, 256), 256, 0, stream>>>(
      xm, 256, proj_w, 256, out, nullptr, proj_b, nullptr, nullptr);
}

// Round 2
// 705.601 us; speedup vs baseline: 4.7494x; 4.7494x over previous
//
#include <hip/hip_runtime.h>
#include <math.h>

// Problem constants
#define LSEQ   4096       // H*W
#define BSZ    4
#define DMODEL 256
#define DINNER 512
#define NROWS  16384      // B*L
#define CHUNK  64
#define NCHUNK 64         // LSEQ / CHUNK

__device__ __forceinline__ float silu_f(float v){ return v / (1.f + __expf(-v)); }
__device__ __forceinline__ float softplus_f(float v){
  return v > 0.f ? v + log1pf(__expf(-v)) : log1pf(__expf(v));
}

// ---------------- LayerNorm over channel dim ----------------
__global__ __launch_bounds__(256) void ln_kernel(const float* __restrict__ x,
    const float* __restrict__ w, const float* __restrict__ bias,
    float* __restrict__ xn)
{
  int i = blockIdx.x;            // row = b*4096 + l
  int b = i >> 12, l = i & 4095;
  int c = threadIdx.x;
  float v = x[((size_t)(b*DMODEL + c) << 12) + l];
  __shared__ float s1[256], s2[256];
  s1[c] = v; s2[c] = v*v;
  __syncthreads();
  for (int off = 128; off > 0; off >>= 1){
    if (c < off){ s1[c] += s1[c+off]; s2[c] += s2[c+off]; }
    __syncthreads();
  }
  float mu  = s1[0] * (1.f/256.f);
  float var = s2[0] * (1.f/256.f) - mu*mu;
  float rs  = rsqrtf(var + 1e-5f);
  xn[(size_t)i*DMODEL + c] = (v - mu) * rs * w[c] + bias[c];
}

// ---------------- Generic tiled f32 GEMM: C = A @ W^T ----------------
template<int MODE, int KT>
__global__ __launch_bounds__(256) void gemm_bt(
    const float* __restrict__ A, int lda,
    const float* __restrict__ W, int N,
    float* __restrict__ O1, float* __restrict__ O2,
    const float* __restrict__ bias,
    const float* __restrict__ xsrc,
    const float* __restrict__ sscale)
{
  __shared__ float As[16][68];   // [k][m], stride 68 floats
  __shared__ float Bs[16][68];
  const int tid = threadIdx.x;
  const int tx = tid & 15, ty = tid >> 4;
  const int mb = blockIdx.y * 64, nb = blockIdx.x * 64;
  const int lrow = tid >> 2;       // 0..63
  const int kq = (tid & 3) << 2;   // 0,4,8,12
  float acc[4][4] = {};

  for (int kt = 0; kt < KT; ++kt){
    const int k0 = kt << 4;
    float4 av = *(const float4*)(A + (size_t)(mb + lrow)*lda + k0 + kq);
    float4 bv = make_float4(0.f, 0.f, 0.f, 0.f);
    const int wrow = nb + lrow;
    if (MODE != 1 || wrow < N)
      bv = *(const float4*)(W + (size_t)wrow*(KT*16) + k0 + kq);
    __syncthreads();
    As[kq+0][lrow] = av.x; As[kq+1][lrow] = av.y; As[kq+2][lrow] = av.z; As[kq+3][lrow] = av.w;
    Bs[kq+0][lrow] = bv.x; Bs[kq+1][lrow] = bv.y; Bs[kq+2][lrow] = bv.z; Bs[kq+3][lrow] = bv.w;
    __syncthreads();
    #pragma unroll
    for (int k = 0; k < 16; ++k){
      float4 a = *(const float4*)&As[k][ty << 2];
      float4 b = *(const float4*)&Bs[k][tx << 2];
      acc[0][0] = fmaf(a.x, b.x, acc[0][0]); acc[0][1] = fmaf(a.x, b.y, acc[0][1]);
      acc[0][2] = fmaf(a.x, b.z, acc[0][2]); acc[0][3] = fmaf(a.x, b.w, acc[0][3]);
      acc[1][0] = fmaf(a.y, b.x, acc[1][0]); acc[1][1] = fmaf(a.y, b.y, acc[1][1]);
      acc[1][2] = fmaf(a.y, b.z, acc[1][2]); acc[1][3] = fmaf(a.y, b.w, acc[1][3]);
      acc[2][0] = fmaf(a.z, b.x, acc[2][0]); acc[2][1] = fmaf(a.z, b.y, acc[2][1]);
      acc[2][2] = fmaf(a.z, b.z, acc[2][2]); acc[2][3] = fmaf(a.z, b.w, acc[2][3]);
      acc[3][0] = fmaf(a.w, b.x, acc[3][0]); acc[3][1] = fmaf(a.w, b.y, acc[3][1]);
      acc[3][2] = fmaf(a.w, b.z, acc[3][2]); acc[3][3] = fmaf(a.w, b.w, acc[3][3]);
    }
  }

  #pragma unroll
  for (int i2 = 0; i2 < 4; ++i2){
    int mg = mb + (ty << 2) + i2;
    #pragma unroll
    for (int j = 0; j < 4; ++j){
      int ng = nb + (tx << 2) + j;
      float v = acc[i2][j];
      if (MODE == 0){
        if (ng < DINNER) O1[(size_t)mg*DINNER + ng] = v;
        else             O2[(size_t)mg*DINNER + (ng - DINNER)] = v;
      } else if (MODE == 1){
        if (ng < N) O1[(size_t)mg*48 + ng] = v;
      } else if (MODE == 2){
        int b = mg >> 12, l = mg & 4095;
        O1[(size_t)mg*DMODEL + ng] =
            v + sscale[0] * xsrc[((size_t)(b*DMODEL + ng) << 12) + l];
      } else if (MODE == 3){
        int b = mg >> 12, l = mg & 4095;
        O1[((size_t)(b*DMODEL + ng) << 12) + l] = v + bias[ng];
      } else { // MODE 4
        O1[(size_t)mg*DINNER + ng] = softplus_f(v + bias[ng]);
      }
    }
  }
}

// ---------------- Causal depthwise conv (width 4) + SiLU ----------------
__global__ __launch_bounds__(256) void conv_silu(const float* __restrict__ xin,
    const float* __restrict__ w, const float* __restrict__ cb,
    float* __restrict__ xc)
{
  int idx = blockIdx.x * 256 + threadIdx.x;  // over 16384*512
  int d = idx & 511;
  int i = idx >> 9;          // b*4096 + l
  int l = i & 4095;
  float acc = cb[d];
  #pragma unroll
  for (int j = 0; j < 4; ++j){
    int ls = l - 3 + j;
    if (ls >= 0) acc = fmaf(w[(d << 2) + j], xin[(size_t)(i - 3 + j)*512 + d], acc);
  }
  xc[idx] = silu_f(acc);
}

// ---------------- Chunk-parallel selective scan ----------------
// Wave lane layout: lane = 16*d_sub + n  (4 channels x 16 states).
// Wave id w in [0, 32768): b = w>>13, chunk = (w>>7)&63, dg = w&127.

// Phase A: local scan per chunk from h=0; store chunk-final h and dt-sum.
__global__ __launch_bounds__(256) void scan_phaseA(
    const float* __restrict__ u, const float* __restrict__ dt,
    const float* __restrict__ dbl, const float* __restrict__ A_log,
    float* __restrict__ hstate,   // (NCHUNK, 32768) : [chunk][(b*512+d)*16+n]
    float* __restrict__ dtsum)    // (NCHUNK, 2048)  : [chunk][b*512+d]
{
  int w = (blockIdx.x * 256 + threadIdx.x) >> 6;
  int lane = threadIdx.x & 63;
  int b = w >> 13;
  int chunk = (w >> 7) & (NCHUNK - 1);
  int dg = w & 127;
  int d = dg * 4 + (lane >> 4);
  int n = lane & 15;
  float Acoef = -__expf(A_log[d*16 + n]);
  float h = 0.f, dacc = 0.f;
  size_t row = (size_t)b * LSEQ + (size_t)chunk * CHUNK;
  #pragma unroll 4
  for (int t = 0; t < CHUNK; ++t, ++row){
    float dtv = dt[row*512 + d];
    float uv  = u[row*512 + d];
    float Bv  = dbl[row*48 + 16 + n];
    h = fmaf(h, __expf(dtv * Acoef), dtv * uv * Bv);
    dacc += dtv;
  }
  hstate[(size_t)chunk*32768 + (size_t)(b*512 + d)*16 + n] = h;
  if (n == 0) dtsum[chunk*2048 + b*512 + d] = dacc;
}

// Combine: sequential over chunks per (b,d,n); overwrite hstate with h_init.
__global__ __launch_bounds__(256) void scan_combine(
    const float* __restrict__ A_log,
    float* __restrict__ hstate, const float* __restrict__ dtsum)
{
  int idx = blockIdx.x * 256 + threadIdx.x;  // 0..32767
  int n = idx & 15, dd = idx >> 4;           // dd = b*512+d
  int d = dd & 511;
  float Acoef = -__expf(A_log[d*16 + n]);
  float H = 0.f;
  for (int c = 0; c < NCHUNK; ++c){
    float S = dtsum[c*2048 + dd];
    float tmp = hstate[(size_t)c*32768 + idx];
    hstate[(size_t)c*32768 + idx] = H;       // h_init for chunk c
    H = fmaf(H, __expf(Acoef * S), tmp);
  }
}

// Phase B: rescan with true h_init, produce gated y.
__global__ __launch_bounds__(256) void scan_phaseB(
    const float* __restrict__ u, const float* __restrict__ dt,
    const float* __restrict__ dbl, const float* __restrict__ A_log,
    const float* __restrict__ Dp, const float* __restrict__ z,
    const float* __restrict__ hstate,
    float* __restrict__ y)
{
  int w = (blockIdx.x * 256 + threadIdx.x) >> 6;
  int lane = threadIdx.x & 63;
  int b = w >> 13;
  int chunk = (w >> 7) & (NCHUNK - 1);
  int dg = w & 127;
  int d = dg * 4 + (lane >> 4);
  int n = lane & 15;
  float Acoef = -__expf(A_log[d*16 + n]);
  float Dv = Dp[d];
  float h = hstate[(size_t)chunk*32768 + (size_t)(b*512 + d)*16 + n];
  size_t row = (size_t)b * LSEQ + (size_t)chunk * CHUNK;
  #pragma unroll 2
  for (int t = 0; t < CHUNK; ++t, ++row){
    float dtv = dt[row*512 + d];
    float uv  = u[row*512 + d];
    float Bv  = dbl[row*48 + 16 + n];
    float Cv  = dbl[row*48 + 32 + n];
    h = fmaf(h, __expf(dtv * Acoef), dtv * uv * Bv);
    float py = h * Cv;
    py += __shfl_xor(py, 1);
    py += __shfl_xor(py, 2);
    py += __shfl_xor(py, 4);
    py += __shfl_xor(py, 8);
    if (n == 0){
      float zv = z[row*512 + d];
      y[row*512 + d] = (py + uv * Dv) * silu_f(zv);
    }
  }
}

extern "C" void kernel_launch(void* const* d_in, const int* in_sizes, int n_in,
                              void* d_out, int out_size, void* d_ws, size_t ws_size,
                              hipStream_t stream)
{
  const float* x          = (const float*)d_in[0];   // (4,256,64,64)
  const float* norm_w     = (const float*)d_in[1];
  const float* norm_b     = (const float*)d_in[2];
  const float* in_proj_w  = (const float*)d_in[3];   // (1024,256)
  const float* conv_w     = (const float*)d_in[4];   // (512,1,4)
  const float* conv_b     = (const float*)d_in[5];
  const float* x_proj_w   = (const float*)d_in[6];   // (48,512)
  const float* dt_proj_w  = (const float*)d_in[7];   // (512,16)
  const float* dt_proj_b  = (const float*)d_in[8];
  const float* A_log      = (const float*)d_in[9];   // (512,16)
  const float* D_ssm      = (const float*)d_in[10];
  const float* out_proj_w = (const float*)d_in[11];  // (256,512)
  const float* proj_w     = (const float*)d_in[12];  // (256,256)
  const float* proj_b     = (const float*)d_in[13];
  const float* skip_scale = (const float*)d_in[14];
  float* out = (float*)d_out;

  char* ws = (char*)d_ws;
  float* xn  = (float*)(ws);                        // 16 MB  [0,16)
  float* xin = (float*)(ws + ((size_t)16 << 20));   // 32 MB  [16,48)
  float* zb  = (float*)(ws + ((size_t)48 << 20));   // 32 MB  [48,80)
  float* xc  = (float*)(ws + ((size_t)80 << 20));   // 32 MB  [80,112)
  float* dbl = (float*)(ws + ((size_t)112 << 20));  //  3 MB  [112,115)
  float* dtb = (float*)(ws + ((size_t)115 << 20));  // 32 MB  [115,147)
  float* yb  = (float*)(ws + ((size_t)16 << 20));   // reuse xin slot
  float* xm  = (float*)(ws);                        // reuse xn slot
  // Scan scratch reuses the xn slot (free after in_proj, until xm in step 7):
  float* hstate = (float*)(ws);                     // 8 MB   [0,8)
  float* dtsum  = (float*)(ws + ((size_t)8 << 20)); // 0.5 MB [8,8.5)

  // 1) LayerNorm
  ln_kernel<<<NROWS, 256, 0, stream>>>(x, norm_w, norm_b, xn);

  // 2) in_proj: (16384,256)@(256->1024), split into xin / z
  gemm_bt<0, 16><<<dim3(16, 256), 256, 0, stream>>>(
      xn, 256, in_proj_w, 1024, xin, zb, nullptr, nullptr, nullptr);

  // 3) causal conv + SiLU
  conv_silu<<<(NROWS * DINNER) / 256, 256, 0, stream>>>(xin, conv_w, conv_b, xc);

  // 4) x_proj: (16384,512)@(512->48)
  gemm_bt<1, 32><<<dim3(1, 256), 256, 0, stream>>>(
      xc, 512, x_proj_w, 48, dbl, nullptr, nullptr, nullptr, nullptr);

  // 5) dt_proj + softplus: (16384,16)@(16->512)
  gemm_bt<4, 1><<<dim3(8, 256), 256, 0, stream>>>(
      dbl, 48, dt_proj_w, 512, dtb, nullptr, dt_proj_b, nullptr, nullptr);

  // 6) chunk-parallel selective scan
  scan_phaseA<<<8192, 256, 0, stream>>>(xc, dtb, dbl, A_log, hstate, dtsum);
  scan_combine<<<128, 256, 0, stream>>>(A_log, hstate, dtsum);
  scan_phaseB<<<8192, 256, 0, stream>>>(xc, dtb, dbl, A_log, D_ssm, zb, hstate, yb);

  // 7) out_proj + skip: (16384,512)@(512->256)
  gemm_bt<2, 32><<<dim3(4, 256), 256, 0, stream>>>(
      yb, 512, out_proj_w, 256, xm, nullptr, nullptr, x, skip_scale);

  // 8) final proj + bias, transposed store
  gemm_bt<3, 16><<<dim3(4, 256), 256, 0, stream>>>(
      xm, 256, proj_w, 256, out, nullptr, proj_b, nullptr, nullptr);
}

// Round 3
// 533.605 us; speedup vs baseline: 6.2802x; 1.3223x over previous
//
#include <hip/hip_runtime.h>
#include <math.h>

// Problem constants
#define LSEQ   4096       // H*W
#define BSZ    4
#define DMODEL 256
#define DINNER 512
#define NROWS  16384      // B*L
#define CHUNK  64
#define NCHUNK 64         // LSEQ / CHUNK

typedef __attribute__((ext_vector_type(8))) short short8;
typedef __attribute__((ext_vector_type(4))) float float4v;

__device__ __forceinline__ float silu_f(float v){ return v / (1.f + __expf(-v)); }
__device__ __forceinline__ float softplus_f(float v){
  return v > 0.f ? v + log1pf(__expf(-v)) : log1pf(__expf(v));
}
__device__ __forceinline__ short f2bf(float x){   // RNE f32 -> bf16 bits
  unsigned int u = __float_as_uint(x);
  unsigned int r = (u + 0x7fffu + ((u >> 16) & 1u)) >> 16;
  return (short)r;
}

// ---------------- LayerNorm over channel dim ----------------
__global__ __launch_bounds__(256) void ln_kernel(const float* __restrict__ x,
    const float* __restrict__ w, const float* __restrict__ bias,
    float* __restrict__ xn)
{
  int i = blockIdx.x;            // row = b*4096 + l
  int b = i >> 12, l = i & 4095;
  int c = threadIdx.x;
  float v = x[((size_t)(b*DMODEL + c) << 12) + l];
  __shared__ float s1[256], s2[256];
  s1[c] = v; s2[c] = v*v;
  __syncthreads();
  for (int off = 128; off > 0; off >>= 1){
    if (c < off){ s1[c] += s1[c+off]; s2[c] += s2[c+off]; }
    __syncthreads();
  }
  float mu  = s1[0] * (1.f/256.f);
  float var = s2[0] * (1.f/256.f) - mu*mu;
  float rs  = rsqrtf(var + 1e-5f);
  xn[(size_t)i*DMODEL + c] = (v - mu) * rs * w[c] + bias[c];
}

// ---------------- bf16 MFMA GEMM: D = A @ W^T (f32 in/out) ----------------
// A: (M, lda) f32 row-major; W: (N, ldw) f32 row-major. Block tile MT*16 x NT*16.
// K = K16 ? 16 (zero-padded to 32) : KT*32.
// MODE 0: split write at col 512 (in_proj)
// MODE 1: stride-48 write, guard ng<N (x_proj)
// MODE 2: + skip_scale * x^T read (out_proj)
// MODE 3: operand-swapped final proj: store out[(b*256+mg)*4096+l] + bias[mg]
// MODE 4: softplus(v + bias[ng]) (dt_proj)
template<int MODE, int MT, int NT, int KT, bool K16>
__global__ __launch_bounds__(256) void gemm_mfma(
    const float* __restrict__ A, int lda,
    const float* __restrict__ W, int ldw, int N,
    float* __restrict__ O1, float* __restrict__ O2,
    const float* __restrict__ bias,
    const float* __restrict__ xsrc, const float* __restrict__ sscale)
{
  constexpr int AROWS = MT*16, BROWS = NT*16;
  constexpr int WM = MT/4;          // m-tiles per wave
  constexpr int CA = MT/4, CB = NT/4; // staging chunks per thread
  __shared__ __align__(16) short As[AROWS*40];
  __shared__ __align__(16) short Bs[BROWS*40];
  const int tid = threadIdx.x;
  const int lane = tid & 63, w = tid >> 6;
  const int ml = lane & 15, quad = lane >> 4;
  const int mb = blockIdx.y * AROWS, nb = blockIdx.x * BROWS;

  float4v acc[WM][NT];
  #pragma unroll
  for (int im = 0; im < WM; ++im)
    #pragma unroll
    for (int j = 0; j < NT; ++j)
      acc[im][j] = (float4v){0.f, 0.f, 0.f, 0.f};

  for (int kt = 0; kt < KT; ++kt){
    const int k0 = kt * 32;
    float4 a0[CA], a1[CA], b0[CB], b1[CB];
    #pragma unroll
    for (int c = 0; c < CA; ++c){
      int chunk = tid + c*256, row = chunk >> 2, q = chunk & 3;
      if (K16 && q >= 2){
        a0[c] = make_float4(0,0,0,0); a1[c] = make_float4(0,0,0,0);
      } else {
        const float* p = A + (size_t)(mb+row)*lda + k0 + q*8;
        a0[c] = *(const float4*)p; a1[c] = *(const float4*)(p+4);
      }
    }
    #pragma unroll
    for (int c = 0; c < CB; ++c){
      int chunk = tid + c*256, row = chunk >> 2, q = chunk & 3;
      bool ok = !(K16 && q >= 2) && !(MODE == 1 && (nb + row) >= N);
      if (ok){
        const float* p = W + (size_t)(nb+row)*ldw + k0 + q*8;
        b0[c] = *(const float4*)p; b1[c] = *(const float4*)(p+4);
      } else {
        b0[c] = make_float4(0,0,0,0); b1[c] = make_float4(0,0,0,0);
      }
    }
    __syncthreads();
    #pragma unroll
    for (int c = 0; c < CA; ++c){
      int chunk = tid + c*256, row = chunk >> 2, q = chunk & 3;
      short8 s;
      s[0]=f2bf(a0[c].x); s[1]=f2bf(a0[c].y); s[2]=f2bf(a0[c].z); s[3]=f2bf(a0[c].w);
      s[4]=f2bf(a1[c].x); s[5]=f2bf(a1[c].y); s[6]=f2bf(a1[c].z); s[7]=f2bf(a1[c].w);
      *(short8*)&As[row*40 + q*8] = s;
    }
    #pragma unroll
    for (int c = 0; c < CB; ++c){
      int chunk = tid + c*256, row = chunk >> 2, q = chunk & 3;
      short8 s;
      s[0]=f2bf(b0[c].x); s[1]=f2bf(b0[c].y); s[2]=f2bf(b0[c].z); s[3]=f2bf(b0[c].w);
      s[4]=f2bf(b1[c].x); s[5]=f2bf(b1[c].y); s[6]=f2bf(b1[c].z); s[7]=f2bf(b1[c].w);
      *(short8*)&Bs[row*40 + q*8] = s;
    }
    __syncthreads();

    short8 af[WM];
    #pragma unroll
    for (int im = 0; im < WM; ++im)
      af[im] = *(const short8*)&As[((w*WM+im)*16 + ml)*40 + quad*8];
    #pragma unroll
    for (int j = 0; j < NT; ++j){
      short8 bf = *(const short8*)&Bs[(j*16 + ml)*40 + quad*8];
      #pragma unroll
      for (int im = 0; im < WM; ++im)
        acc[im][j] = __builtin_amdgcn_mfma_f32_16x16x32_bf16(af[im], bf, acc[im][j], 0, 0, 0);
    }
  }

  #pragma unroll
  for (int im = 0; im < WM; ++im){
    const int mt0 = mb + (w*WM + im)*16 + quad*4;
    #pragma unroll
    for (int j = 0; j < NT; ++j){
      const int ng = nb + j*16 + ml;
      #pragma unroll
      for (int r = 0; r < 4; ++r){
        int mg = mt0 + r;
        float v = acc[im][j][r];
        if (MODE == 0){
          if (ng < DINNER) O1[(size_t)mg*DINNER + ng] = v;
          else             O2[(size_t)mg*DINNER + (ng - DINNER)] = v;
        } else if (MODE == 1){
          if (ng < N) O1[(size_t)mg*48 + ng] = v;
        } else if (MODE == 2){
          int b = mg >> 12, l = mg & 4095;
          O1[(size_t)mg*DMODEL + ng] =
              v + sscale[0] * xsrc[((size_t)(b*DMODEL + ng) << 12) + l];
        } else if (MODE == 3){
          int b = ng >> 12, l = ng & 4095;
          O1[((size_t)(b*DMODEL + mg) << 12) + l] = v + bias[mg];
        } else { // MODE 4
          O1[(size_t)mg*DINNER + ng] = softplus_f(v + bias[ng]);
        }
      }
    }
  }
}

// ---------------- Causal depthwise conv (width 4) + SiLU ----------------
__global__ __launch_bounds__(256) void conv_silu(const float* __restrict__ xin,
    const float* __restrict__ w, const float* __restrict__ cb,
    float* __restrict__ xc)
{
  int idx = blockIdx.x * 256 + threadIdx.x;  // over 16384*512
  int d = idx & 511;
  int i = idx >> 9;          // b*4096 + l
  int l = i & 4095;
  float acc = cb[d];
  #pragma unroll
  for (int j = 0; j < 4; ++j){
    int ls = l - 3 + j;
    if (ls >= 0) acc = fmaf(w[(d << 2) + j], xin[(size_t)(i - 3 + j)*512 + d], acc);
  }
  xc[idx] = silu_f(acc);
}

// ---------------- Chunk-parallel selective scan ----------------
// Phase A: local scan per chunk from h=0; store chunk-final h and dt-sum.
__global__ __launch_bounds__(256) void scan_phaseA(
    const float* __restrict__ u, const float* __restrict__ dt,
    const float* __restrict__ dbl, const float* __restrict__ A_log,
    float* __restrict__ hstate,   // (NCHUNK, 32768)
    float* __restrict__ dtsum)    // (NCHUNK, 2048)
{
  int w = (blockIdx.x * 256 + threadIdx.x) >> 6;
  int lane = threadIdx.x & 63;
  int b = w >> 13;
  int chunk = (w >> 7) & (NCHUNK - 1);
  int dg = w & 127;
  int d = dg * 4 + (lane >> 4);
  int n = lane & 15;
  float Acoef = -__expf(A_log[d*16 + n]);
  float h = 0.f, dacc = 0.f;
  size_t row = (size_t)b * LSEQ + (size_t)chunk * CHUNK;
  #pragma unroll 4
  for (int t = 0; t < CHUNK; ++t, ++row){
    float dtv = dt[row*512 + d];
    float uv  = u[row*512 + d];
    float Bv  = dbl[row*48 + 16 + n];
    h = fmaf(h, __expf(dtv * Acoef), dtv * uv * Bv);
    dacc += dtv;
  }
  hstate[(size_t)chunk*32768 + (size_t)(b*512 + d)*16 + n] = h;
  if (n == 0) dtsum[chunk*2048 + b*512 + d] = dacc;
}

// Combine: sequential over chunks per (b,d,n); overwrite hstate with h_init.
__global__ __launch_bounds__(256) void scan_combine(
    const float* __restrict__ A_log,
    float* __restrict__ hstate, const float* __restrict__ dtsum)
{
  int idx = blockIdx.x * 256 + threadIdx.x;  // 0..32767
  int n = idx & 15, dd = idx >> 4;           // dd = b*512+d
  int d = dd & 511;
  float Acoef = -__expf(A_log[d*16 + n]);
  float H = 0.f;
  for (int c = 0; c < NCHUNK; ++c){
    float S = dtsum[c*2048 + dd];
    float tmp = hstate[(size_t)c*32768 + idx];
    hstate[(size_t)c*32768 + idx] = H;       // h_init for chunk c
    H = fmaf(H, __expf(Acoef * S), tmp);
  }
}

// Phase B: rescan with true h_init, produce gated y.
__global__ __launch_bounds__(256) void scan_phaseB(
    const float* __restrict__ u, const float* __restrict__ dt,
    const float* __restrict__ dbl, const float* __restrict__ A_log,
    const float* __restrict__ Dp, const float* __restrict__ z,
    const float* __restrict__ hstate,
    float* __restrict__ y)
{
  int w = (blockIdx.x * 256 + threadIdx.x) >> 6;
  int lane = threadIdx.x & 63;
  int b = w >> 13;
  int chunk = (w >> 7) & (NCHUNK - 1);
  int dg = w & 127;
  int d = dg * 4 + (lane >> 4);
  int n = lane & 15;
  float Acoef = -__expf(A_log[d*16 + n]);
  float Dv = Dp[d];
  float h = hstate[(size_t)chunk*32768 + (size_t)(b*512 + d)*16 + n];
  size_t row = (size_t)b * LSEQ + (size_t)chunk * CHUNK;
  #pragma unroll 2
  for (int t = 0; t < CHUNK; ++t, ++row){
    float dtv = dt[row*512 + d];
    float uv  = u[row*512 + d];
    float Bv  = dbl[row*48 + 16 + n];
    float Cv  = dbl[row*48 + 32 + n];
    h = fmaf(h, __expf(dtv * Acoef), dtv * uv * Bv);
    float py = h * Cv;
    py += __shfl_xor(py, 1);
    py += __shfl_xor(py, 2);
    py += __shfl_xor(py, 4);
    py += __shfl_xor(py, 8);
    if (n == 0){
      float zv = z[row*512 + d];
      y[row*512 + d] = (py + uv * Dv) * silu_f(zv);
    }
  }
}

extern "C" void kernel_launch(void* const* d_in, const int* in_sizes, int n_in,
                              void* d_out, int out_size, void* d_ws, size_t ws_size,
                              hipStream_t stream)
{
  const float* x          = (const float*)d_in[0];   // (4,256,64,64)
  const float* norm_w     = (const float*)d_in[1];
  const float* norm_b     = (const float*)d_in[2];
  const float* in_proj_w  = (const float*)d_in[3];   // (1024,256)
  const float* conv_w     = (const float*)d_in[4];   // (512,1,4)
  const float* conv_b     = (const float*)d_in[5];
  const float* x_proj_w   = (const float*)d_in[6];   // (48,512)
  const float* dt_proj_w  = (const float*)d_in[7];   // (512,16)
  const float* dt_proj_b  = (const float*)d_in[8];
  const float* A_log      = (const float*)d_in[9];   // (512,16)
  const float* D_ssm      = (const float*)d_in[10];
  const float* out_proj_w = (const float*)d_in[11];  // (256,512)
  const float* proj_w     = (const float*)d_in[12];  // (256,256)
  const float* proj_b     = (const float*)d_in[13];
  const float* skip_scale = (const float*)d_in[14];
  float* out = (float*)d_out;

  char* ws = (char*)d_ws;
  float* xn  = (float*)(ws);                        // 16 MB  [0,16)
  float* xin = (float*)(ws + ((size_t)16 << 20));   // 32 MB  [16,48)
  float* zb  = (float*)(ws + ((size_t)48 << 20));   // 32 MB  [48,80)
  float* xc  = (float*)(ws + ((size_t)80 << 20));   // 32 MB  [80,112)
  float* dbl = (float*)(ws + ((size_t)112 << 20));  //  3 MB  [112,115)
  float* dtb = (float*)(ws + ((size_t)115 << 20));  // 32 MB  [115,147)
  float* yb  = (float*)(ws + ((size_t)16 << 20));   // reuse xin slot
  float* xm  = (float*)(ws);                        // reuse xn slot
  float* hstate = (float*)(ws);                     // 8 MB   (xn slot, free after in_proj)
  float* dtsum  = (float*)(ws + ((size_t)8 << 20)); // 0.5 MB

  // 1) LayerNorm
  ln_kernel<<<NROWS, 256, 0, stream>>>(x, norm_w, norm_b, xn);

  // 2) in_proj: (16384,1024,256) MFMA, split into xin / z
  gemm_mfma<0, 8, 8, 8, false><<<dim3(8, 128), 256, 0, stream>>>(
      xn, 256, in_proj_w, 256, 1024, xin, zb, nullptr, nullptr, nullptr);

  // 3) causal conv + SiLU
  conv_silu<<<(NROWS * DINNER) / 256, 256, 0, stream>>>(xin, conv_w, conv_b, xc);

  // 4) x_proj: (16384,48,512)
  gemm_mfma<1, 4, 4, 16, false><<<dim3(1, 256), 256, 0, stream>>>(
      xc, 512, x_proj_w, 512, 48, dbl, nullptr, nullptr, nullptr, nullptr);

  // 5) dt_proj + softplus: (16384,512,16)
  gemm_mfma<4, 4, 4, 1, true><<<dim3(8, 256), 256, 0, stream>>>(
      dbl, 48, dt_proj_w, 16, 512, dtb, nullptr, dt_proj_b, nullptr, nullptr);

  // 6) chunk-parallel selective scan
  scan_phaseA<<<8192, 256, 0, stream>>>(xc, dtb, dbl, A_log, hstate, dtsum);
  scan_combine<<<128, 256, 0, stream>>>(A_log, hstate, dtsum);
  scan_phaseB<<<8192, 256, 0, stream>>>(xc, dtb, dbl, A_log, D_ssm, zb, hstate, yb);

  // 7) out_proj + skip: (16384,256,512)
  gemm_mfma<2, 8, 8, 16, false><<<dim3(2, 128), 256, 0, stream>>>(
      yb, 512, out_proj_w, 512, 256, xm, nullptr, nullptr, x, skip_scale);

  // 8) final proj (operand-swapped): D = proj_w @ xm^T -> coalesced (B,C,L) store
  gemm_mfma<3, 8, 8, 8, false><<<dim3(128, 2), 256, 0, stream>>>(
      proj_w, 256, xm, 256, 16384, out, nullptr, proj_b, nullptr, nullptr);
}

// Round 4
// 451.200 us; speedup vs baseline: 7.4272x; 1.1826x over previous
//
#include <hip/hip_runtime.h>
#include <math.h>

// Problem constants
#define LSEQ   4096       // H*W
#define BSZ    4
#define DMODEL 256
#define DINNER 512
#define NROWS  16384      // B*L
#define CHUNK  64
#define NCHUNK 64         // LSEQ / CHUNK

typedef __attribute__((ext_vector_type(8))) short short8;
typedef __attribute__((ext_vector_type(4))) float float4v;

__device__ __forceinline__ float silu_f(float v){ return v / (1.f + __expf(-v)); }
__device__ __forceinline__ float softplus_f(float v){
  return v > 0.f ? v + log1pf(__expf(-v)) : log1pf(__expf(v));
}
__device__ __forceinline__ short f2bf(float x){   // RNE f32 -> bf16 bits
  unsigned int u = __float_as_uint(x);
  unsigned int r = (u + 0x7fffu + ((u >> 16) & 1u)) >> 16;
  return (short)r;
}

// ---------------- LayerNorm over channel dim ----------------
__global__ __launch_bounds__(256) void ln_kernel(const float* __restrict__ x,
    const float* __restrict__ w, const float* __restrict__ bias,
    float* __restrict__ xn)
{
  int i = blockIdx.x;            // row = b*4096 + l
  int b = i >> 12, l = i & 4095;
  int c = threadIdx.x;
  float v = x[((size_t)(b*DMODEL + c) << 12) + l];
  __shared__ float s1[256], s2[256];
  s1[c] = v; s2[c] = v*v;
  __syncthreads();
  for (int off = 128; off > 0; off >>= 1){
    if (c < off){ s1[c] += s1[c+off]; s2[c] += s2[c+off]; }
    __syncthreads();
  }
  float mu  = s1[0] * (1.f/256.f);
  float var = s2[0] * (1.f/256.f) - mu*mu;
  float rs  = rsqrtf(var + 1e-5f);
  xn[(size_t)i*DMODEL + c] = (v - mu) * rs * w[c] + bias[c];
}

// ---------------- bf16 MFMA GEMM: D = A @ W^T (f32 in/out) ----------------
// MODE 0: split write at col 512 (in_proj)
// MODE 1: stride-48 write, guard ng<N (x_proj)
// MODE 2: + skip_scale * x^T read (out_proj)
// MODE 3: operand-swapped final proj: store out[(b*256+mg)*4096+l] + bias[mg]
// MODE 4: softplus(v + bias[ng]) (dt_proj)
template<int MODE, int MT, int NT, int KT, bool K16>
__global__ __launch_bounds__(256) void gemm_mfma(
    const float* __restrict__ A, int lda,
    const float* __restrict__ W, int ldw, int N,
    float* __restrict__ O1, float* __restrict__ O2,
    const float* __restrict__ bias,
    const float* __restrict__ xsrc, const float* __restrict__ sscale)
{
  constexpr int AROWS = MT*16, BROWS = NT*16;
  constexpr int WM = MT/4;          // m-tiles per wave
  constexpr int CA = MT/4, CB = NT/4; // staging chunks per thread
  __shared__ __align__(16) short As[AROWS*40];
  __shared__ __align__(16) short Bs[BROWS*40];
  const int tid = threadIdx.x;
  const int lane = tid & 63, w = tid >> 6;
  const int ml = lane & 15, quad = lane >> 4;
  const int mb = blockIdx.y * AROWS, nb = blockIdx.x * BROWS;

  float4v acc[WM][NT];
  #pragma unroll
  for (int im = 0; im < WM; ++im)
    #pragma unroll
    for (int j = 0; j < NT; ++j)
      acc[im][j] = (float4v){0.f, 0.f, 0.f, 0.f};

  for (int kt = 0; kt < KT; ++kt){
    const int k0 = kt * 32;
    float4 a0[CA], a1[CA], b0[CB], b1[CB];
    #pragma unroll
    for (int c = 0; c < CA; ++c){
      int chunk = tid + c*256, row = chunk >> 2, q = chunk & 3;
      if (K16 && q >= 2){
        a0[c] = make_float4(0,0,0,0); a1[c] = make_float4(0,0,0,0);
      } else {
        const float* p = A + (size_t)(mb+row)*lda + k0 + q*8;
        a0[c] = *(const float4*)p; a1[c] = *(const float4*)(p+4);
      }
    }
    #pragma unroll
    for (int c = 0; c < CB; ++c){
      int chunk = tid + c*256, row = chunk >> 2, q = chunk & 3;
      bool ok = !(K16 && q >= 2) && !(MODE == 1 && (nb + row) >= N);
      if (ok){
        const float* p = W + (size_t)(nb+row)*ldw + k0 + q*8;
        b0[c] = *(const float4*)p; b1[c] = *(const float4*)(p+4);
      } else {
        b0[c] = make_float4(0,0,0,0); b1[c] = make_float4(0,0,0,0);
      }
    }
    __syncthreads();
    #pragma unroll
    for (int c = 0; c < CA; ++c){
      int chunk = tid + c*256, row = chunk >> 2, q = chunk & 3;
      short8 s;
      s[0]=f2bf(a0[c].x); s[1]=f2bf(a0[c].y); s[2]=f2bf(a0[c].z); s[3]=f2bf(a0[c].w);
      s[4]=f2bf(a1[c].x); s[5]=f2bf(a1[c].y); s[6]=f2bf(a1[c].z); s[7]=f2bf(a1[c].w);
      *(short8*)&As[row*40 + q*8] = s;
    }
    #pragma unroll
    for (int c = 0; c < CB; ++c){
      int chunk = tid + c*256, row = chunk >> 2, q = chunk & 3;
      short8 s;
      s[0]=f2bf(b0[c].x); s[1]=f2bf(b0[c].y); s[2]=f2bf(b0[c].z); s[3]=f2bf(b0[c].w);
      s[4]=f2bf(b1[c].x); s[5]=f2bf(b1[c].y); s[6]=f2bf(b1[c].z); s[7]=f2bf(b1[c].w);
      *(short8*)&Bs[row*40 + q*8] = s;
    }
    __syncthreads();

    short8 af[WM];
    #pragma unroll
    for (int im = 0; im < WM; ++im)
      af[im] = *(const short8*)&As[((w*WM+im)*16 + ml)*40 + quad*8];
    #pragma unroll
    for (int j = 0; j < NT; ++j){
      short8 bf = *(const short8*)&Bs[(j*16 + ml)*40 + quad*8];
      #pragma unroll
      for (int im = 0; im < WM; ++im)
        acc[im][j] = __builtin_amdgcn_mfma_f32_16x16x32_bf16(af[im], bf, acc[im][j], 0, 0, 0);
    }
  }

  #pragma unroll
  for (int im = 0; im < WM; ++im){
    const int mt0 = mb + (w*WM + im)*16 + quad*4;
    #pragma unroll
    for (int j = 0; j < NT; ++j){
      const int ng = nb + j*16 + ml;
      #pragma unroll
      for (int r = 0; r < 4; ++r){
        int mg = mt0 + r;
        float v = acc[im][j][r];
        if (MODE == 0){
          if (ng < DINNER) O1[(size_t)mg*DINNER + ng] = v;
          else             O2[(size_t)mg*DINNER + (ng - DINNER)] = v;
        } else if (MODE == 1){
          if (ng < N) O1[(size_t)mg*48 + ng] = v;
        } else if (MODE == 2){
          int b = mg >> 12, l = mg & 4095;
          O1[(size_t)mg*DMODEL + ng] =
              v + sscale[0] * xsrc[((size_t)(b*DMODEL + ng) << 12) + l];
        } else if (MODE == 3){
          int b = ng >> 12, l = ng & 4095;
          O1[((size_t)(b*DMODEL + mg) << 12) + l] = v + bias[mg];
        } else { // MODE 4
          O1[(size_t)mg*DINNER + ng] = softplus_f(v + bias[ng]);
        }
      }
    }
  }
}

// ---------------- Causal depthwise conv (width 4) + SiLU ----------------
__global__ __launch_bounds__(256) void conv_silu(const float* __restrict__ xin,
    const float* __restrict__ w, const float* __restrict__ cb,
    float* __restrict__ xc)
{
  int idx = blockIdx.x * 256 + threadIdx.x;  // over 16384*512
  int d = idx & 511;
  int i = idx >> 9;          // b*4096 + l
  int l = i & 4095;
  float acc = cb[d];
  #pragma unroll
  for (int j = 0; j < 4; ++j){
    int ls = l - 3 + j;
    if (ls >= 0) acc = fmaf(w[(d << 2) + j], xin[(size_t)(i - 3 + j)*512 + d], acc);
  }
  xc[idx] = silu_f(acc);
}

// ---------------- Chunk-parallel selective scan ----------------
// Phase A: local scan per chunk from h=0; store chunk-final h and dt-sum.
__global__ __launch_bounds__(256) void scan_phaseA(
    const float* __restrict__ u, const float* __restrict__ dt,
    const float* __restrict__ dbl, const float* __restrict__ A_log,
    float* __restrict__ hstate,   // (NCHUNK, 32768)
    float* __restrict__ dtsum)    // (NCHUNK, 2048)
{
  int w = (blockIdx.x * 256 + threadIdx.x) >> 6;
  int lane = threadIdx.x & 63;
  int b = w >> 13;
  int chunk = (w >> 7) & (NCHUNK - 1);
  int dg = w & 127;
  int d = dg * 4 + (lane >> 4);
  int n = lane & 15;
  float Acoef = -__expf(A_log[d*16 + n]);
  float h = 0.f, dacc = 0.f;
  size_t row = (size_t)b * LSEQ + (size_t)chunk * CHUNK;
  #pragma unroll 4
  for (int t = 0; t < CHUNK; ++t, ++row){
    float dtv = dt[row*512 + d];
    float uv  = u[row*512 + d];
    float Bv  = dbl[row*48 + 16 + n];
    h = fmaf(h, __expf(dtv * Acoef), dtv * uv * Bv);
    dacc += dtv;
  }
  hstate[(size_t)chunk*32768 + (size_t)(b*512 + d)*16 + n] = h;
  if (n == 0) dtsum[chunk*2048 + b*512 + d] = dacc;
}

// Combine: sequential over chunks per (b,d,n); overwrite hstate with h_init.
__global__ __launch_bounds__(256) void scan_combine(
    const float* __restrict__ A_log,
    float* __restrict__ hstate, const float* __restrict__ dtsum)
{
  int idx = blockIdx.x * 256 + threadIdx.x;  // 0..32767
  int n = idx & 15, dd = idx >> 4;           // dd = b*512+d
  int d = dd & 511;
  float Acoef = -__expf(A_log[d*16 + n]);
  float H = 0.f;
  for (int c = 0; c < NCHUNK; ++c){
    float S = dtsum[c*2048 + dd];
    float tmp = hstate[(size_t)c*32768 + idx];
    hstate[(size_t)c*32768 + idx] = H;       // h_init for chunk c
    H = fmaf(H, __expf(Acoef * S), tmp);
  }
}

// Phase B: rescan with true h_init; batched 16-value butterfly reduce,
// deferred gate/store once per 16 steps.
__global__ __launch_bounds__(256) void scan_phaseB(
    const float* __restrict__ u, const float* __restrict__ dt,
    const float* __restrict__ dbl, const float* __restrict__ A_log,
    const float* __restrict__ Dp, const float* __restrict__ z,
    const float* __restrict__ hstate,
    float* __restrict__ y)
{
  int w = (blockIdx.x * 256 + threadIdx.x) >> 6;
  int lane = threadIdx.x & 63;
  int b = w >> 13;
  int chunk = (w >> 7) & (NCHUNK - 1);
  int dg = w & 127;
  int d = dg * 4 + (lane >> 4);
  int n = lane & 15;
  float Acoef = -__expf(A_log[d*16 + n]);
  float Dv0 = (n == 0) ? Dp[d] : 0.f;   // u*D folded into the summed slots
  float h = hstate[(size_t)chunk*32768 + (size_t)(b*512 + d)*16 + n];
  size_t row0 = (size_t)b * LSEQ + (size_t)chunk * CHUNK;
  // lane n ends holding the reduced slot tt = brev4(n)
  const int tt_out = ((n&1)<<3) | ((n&2)<<1) | ((n&4)>>1) | ((n&8)>>3);

  for (int batch = 0; batch < 4; ++batch){
    size_t row = row0 + batch*16;
    float py[16];
    #pragma unroll
    for (int tt = 0; tt < 16; ++tt){
      size_t r = row + tt;
      float dtv = dt[r*512 + d];
      float uv  = u[r*512 + d];
      float Bv  = dbl[r*48 + 16 + n];
      float Cv  = dbl[r*48 + 32 + n];
      h = fmaf(h, __expf(dtv * Acoef), dtv * uv * Bv);
      py[tt] = fmaf(uv, Dv0, h * Cv);
    }
    // multi-value butterfly: reduce 16 values over the 16 state lanes
    #pragma unroll
    for (int i = 0; i < 8; ++i){
      float lo = py[i], hi = py[i+8];
      float recv = __shfl_xor((n & 1) ? lo : hi, 1);
      py[i] = ((n & 1) ? hi : lo) + recv;
    }
    #pragma unroll
    for (int i = 0; i < 4; ++i){
      float lo = py[i], hi = py[i+4];
      float recv = __shfl_xor((n & 2) ? lo : hi, 2);
      py[i] = ((n & 2) ? hi : lo) + recv;
    }
    #pragma unroll
    for (int i = 0; i < 2; ++i){
      float lo = py[i], hi = py[i+2];
      float recv = __shfl_xor((n & 4) ? lo : hi, 4);
      py[i] = ((n & 4) ? hi : lo) + recv;
    }
    {
      float lo = py[0], hi = py[1];
      float recv = __shfl_xor((n & 8) ? lo : hi, 8);
      py[0] = ((n & 8) ? hi : lo) + recv;
    }
    size_t re = row + tt_out;
    float zv = z[re*512 + d];
    y[re*512 + d] = py[0] * silu_f(zv);
  }
}

extern "C" void kernel_launch(void* const* d_in, const int* in_sizes, int n_in,
                              void* d_out, int out_size, void* d_ws, size_t ws_size,
                              hipStream_t stream)
{
  const float* x          = (const float*)d_in[0];   // (4,256,64,64)
  const float* norm_w     = (const float*)d_in[1];
  const float* norm_b     = (const float*)d_in[2];
  const float* in_proj_w  = (const float*)d_in[3];   // (1024,256)
  const float* conv_w     = (const float*)d_in[4];   // (512,1,4)
  const float* conv_b     = (const float*)d_in[5];
  const float* x_proj_w   = (const float*)d_in[6];   // (48,512)
  const float* dt_proj_w  = (const float*)d_in[7];   // (512,16)
  const float* dt_proj_b  = (const float*)d_in[8];
  const float* A_log      = (const float*)d_in[9];   // (512,16)
  const float* D_ssm      = (const float*)d_in[10];
  const float* out_proj_w = (const float*)d_in[11];  // (256,512)
  const float* proj_w     = (const float*)d_in[12];  // (256,256)
  const float* proj_b     = (const float*)d_in[13];
  const float* skip_scale = (const float*)d_in[14];
  float* out = (float*)d_out;

  char* ws = (char*)d_ws;
  float* xn  = (float*)(ws);                        // 16 MB  [0,16)
  float* xin = (float*)(ws + ((size_t)16 << 20));   // 32 MB  [16,48)
  float* zb  = (float*)(ws + ((size_t)48 << 20));   // 32 MB  [48,80)
  float* xc  = (float*)(ws + ((size_t)80 << 20));   // 32 MB  [80,112)
  float* dbl = (float*)(ws + ((size_t)112 << 20));  //  3 MB  [112,115)
  float* dtb = (float*)(ws + ((size_t)115 << 20));  // 32 MB  [115,147)
  float* yb  = (float*)(ws + ((size_t)16 << 20));   // reuse xin slot
  float* xm  = (float*)(ws);                        // reuse xn slot
  float* hstate = (float*)(ws);                     // 8 MB   (xn slot, free after in_proj)
  float* dtsum  = (float*)(ws + ((size_t)8 << 20)); // 0.5 MB

  // 1) LayerNorm
  ln_kernel<<<NROWS, 256, 0, stream>>>(x, norm_w, norm_b, xn);

  // 2) in_proj: (16384,1024,256) MFMA, split into xin / z
  gemm_mfma<0, 8, 8, 8, false><<<dim3(8, 128), 256, 0, stream>>>(
      xn, 256, in_proj_w, 256, 1024, xin, zb, nullptr, nullptr, nullptr);

  // 3) causal conv + SiLU
  conv_silu<<<(NROWS * DINNER) / 256, 256, 0, stream>>>(xin, conv_w, conv_b, xc);

  // 4) x_proj: (16384,48,512)
  gemm_mfma<1, 4, 4, 16, false><<<dim3(1, 256), 256, 0, stream>>>(
      xc, 512, x_proj_w, 512, 48, dbl, nullptr, nullptr, nullptr, nullptr);

  // 5) dt_proj + softplus: (16384,512,16)
  gemm_mfma<4, 4, 4, 1, true><<<dim3(8, 256), 256, 0, stream>>>(
      dbl, 48, dt_proj_w, 16, 512, dtb, nullptr, dt_proj_b, nullptr, nullptr);

  // 6) chunk-parallel selective scan
  scan_phaseA<<<8192, 256, 0, stream>>>(xc, dtb, dbl, A_log, hstate, dtsum);
  scan_combine<<<128, 256, 0, stream>>>(A_log, hstate, dtsum);
  scan_phaseB<<<8192, 256, 0, stream>>>(xc, dtb, dbl, A_log, D_ssm, zb, hstate, yb);

  // 7) out_proj + skip: (16384,256,512)
  gemm_mfma<2, 8, 8, 16, false><<<dim3(2, 128), 256, 0, stream>>>(
      yb, 512, out_proj_w, 512, 256, xm, nullptr, nullptr, x, skip_scale);

  // 8) final proj (operand-swapped): D = proj_w @ xm^T -> coalesced (B,C,L) store
  gemm_mfma<3, 8, 8, 8, false><<<dim3(128, 2), 256, 0, stream>>>(
      proj_w, 256, xm, 256, 16384, out, nullptr, proj_b, nullptr, nullptr);
}

// Round 5
// 371.743 us; speedup vs baseline: 9.0147x; 1.2137x over previous
//
#include <hip/hip_runtime.h>
#include <math.h>

// Problem constants
#define LSEQ   4096       // H*W
#define BSZ    4
#define DMODEL 256
#define DINNER 512
#define NROWS  16384      // B*L
#define CHUNK  64
#define NCHUNK 64         // LSEQ / CHUNK

typedef __attribute__((ext_vector_type(8))) short short8;
typedef __attribute__((ext_vector_type(4))) float float4v;

__device__ __forceinline__ float silu_f(float v){ return v / (1.f + __expf(-v)); }
__device__ __forceinline__ float softplus_f(float v){
  return v > 0.f ? v + log1pf(__expf(-v)) : log1pf(__expf(v));
}
__device__ __forceinline__ short f2bf(float x){   // RNE f32 -> bf16 bits
  unsigned int u = __float_as_uint(x);
  unsigned int r = (u + 0x7fffu + ((u >> 16) & 1u)) >> 16;
  return (short)r;
}

// ---------------- weight pre-convert (f32 -> bf16), once per launch ----------------
__global__ __launch_bounds__(256) void convert_w(
    const float* __restrict__ a, const float* __restrict__ b, const float* __restrict__ c,
    short* __restrict__ oa, short* __restrict__ ob, short* __restrict__ oc)
{
  int i = blockIdx.x * 256 + threadIdx.x;
  if (i < 262144) oa[i] = f2bf(a[i]);   // in_proj_w 1024*256
  if (i < 131072) ob[i] = f2bf(b[i]);   // out_proj_w 256*512
  if (i < 65536)  oc[i] = f2bf(c[i]);   // proj_w 256*256
}

// ---------------- LayerNorm over channel dim -> bf16 ----------------
__global__ __launch_bounds__(256) void ln_kernel(const float* __restrict__ x,
    const float* __restrict__ w, const float* __restrict__ bias,
    short* __restrict__ xnb)
{
  int i = blockIdx.x;            // row = b*4096 + l
  int b = i >> 12, l = i & 4095;
  int c = threadIdx.x;
  float v = x[((size_t)(b*DMODEL + c) << 12) + l];
  __shared__ float s1[256], s2[256];
  s1[c] = v; s2[c] = v*v;
  __syncthreads();
  for (int off = 128; off > 0; off >>= 1){
    if (c < off){ s1[c] += s1[c+off]; s2[c] += s2[c+off]; }
    __syncthreads();
  }
  float mu  = s1[0] * (1.f/256.f);
  float var = s2[0] * (1.f/256.f) - mu*mu;
  float rs  = rsqrtf(var + 1e-5f);
  xnb[(size_t)i*DMODEL + c] = f2bf((v - mu) * rs * w[c] + bias[c]);
}

// ---------------- bf16-input MFMA GEMM: D = A @ W^T ----------------
// A: (M,lda) bf16 row-major; W: (N,ldw) bf16 row-major; K = KT*32.
// MODE 0: split f32 write at col 512 (in_proj -> xin, z)
// MODE 2: (v + skip*x^T) -> bf16 xm (out_proj)
// MODE 3: operand-swapped final proj: f32 store out[(b*256+mg)*4096+l] + bias[mg]
template<int MODE, int MT, int NT, int KT>
__global__ __launch_bounds__(256) void gemm_bf16(
    const short* __restrict__ A, int lda,
    const short* __restrict__ W, int ldw,
    float* __restrict__ O1, float* __restrict__ O2, short* __restrict__ Ob,
    const float* __restrict__ bias,
    const float* __restrict__ xsrc, const float* __restrict__ sscale)
{
  constexpr int AROWS = MT*16, BROWS = NT*16;
  constexpr int WM = MT/4;
  constexpr int CA = MT/4, CB = NT/4;   // short8-chunks per thread
  __shared__ __align__(16) short As[AROWS*40];
  __shared__ __align__(16) short Bs[BROWS*40];
  const int tid = threadIdx.x;
  const int lane = tid & 63, w = tid >> 6;
  const int ml = lane & 15, quad = lane >> 4;
  const int mb = blockIdx.y * AROWS, nb = blockIdx.x * BROWS;

  float4v acc[WM][NT];
  #pragma unroll
  for (int im = 0; im < WM; ++im)
    #pragma unroll
    for (int j = 0; j < NT; ++j)
      acc[im][j] = (float4v){0.f, 0.f, 0.f, 0.f};

  for (int kt = 0; kt < KT; ++kt){
    const int k0 = kt * 32;
    short8 av[CA], bv[CB];
    #pragma unroll
    for (int c = 0; c < CA; ++c){
      int id = tid + c*256, row = id >> 2, q = id & 3;
      av[c] = *(const short8*)(A + (size_t)(mb+row)*lda + k0 + q*8);
    }
    #pragma unroll
    for (int c = 0; c < CB; ++c){
      int id = tid + c*256, row = id >> 2, q = id & 3;
      bv[c] = *(const short8*)(W + (size_t)(nb+row)*ldw + k0 + q*8);
    }
    __syncthreads();
    #pragma unroll
    for (int c = 0; c < CA; ++c){
      int id = tid + c*256, row = id >> 2, q = id & 3;
      *(short8*)&As[row*40 + q*8] = av[c];
    }
    #pragma unroll
    for (int c = 0; c < CB; ++c){
      int id = tid + c*256, row = id >> 2, q = id & 3;
      *(short8*)&Bs[row*40 + q*8] = bv[c];
    }
    __syncthreads();

    short8 af[WM];
    #pragma unroll
    for (int im = 0; im < WM; ++im)
      af[im] = *(const short8*)&As[((w*WM+im)*16 + ml)*40 + quad*8];
    #pragma unroll
    for (int j = 0; j < NT; ++j){
      short8 bf = *(const short8*)&Bs[(j*16 + ml)*40 + quad*8];
      #pragma unroll
      for (int im = 0; im < WM; ++im)
        acc[im][j] = __builtin_amdgcn_mfma_f32_16x16x32_bf16(af[im], bf, acc[im][j], 0, 0, 0);
    }
  }

  #pragma unroll
  for (int im = 0; im < WM; ++im){
    const int mt0 = mb + (w*WM + im)*16 + quad*4;
    #pragma unroll
    for (int j = 0; j < NT; ++j){
      const int ng = nb + j*16 + ml;
      #pragma unroll
      for (int r = 0; r < 4; ++r){
        int mg = mt0 + r;
        float v = acc[im][j][r];
        if (MODE == 0){
          if (ng < DINNER) O1[(size_t)mg*DINNER + ng] = v;
          else             O2[(size_t)mg*DINNER + (ng - DINNER)] = v;
        } else if (MODE == 2){
          int b = mg >> 12, l = mg & 4095;
          float vv = v + sscale[0] * xsrc[((size_t)(b*DMODEL + ng) << 12) + l];
          Ob[(size_t)mg*DMODEL + ng] = f2bf(vv);
        } else { // MODE 3
          int b = ng >> 12, l = ng & 4095;
          O1[((size_t)(b*DMODEL + mg) << 12) + l] = v + bias[mg];
        }
      }
    }
  }
}

// ---------------- f32-input MFMA GEMM (small ops: x_proj, dt_proj) ----------------
// MODE 1: stride-48 write, guard ng<N (x_proj)
// MODE 5: operand-swapped dt_proj: softplus(v + bias[mg]) -> O1[mg*16384 + ng]
template<int MODE, int MT, int NT, int KT, bool K16>
__global__ __launch_bounds__(256) void gemm_mfma(
    const float* __restrict__ A, int lda,
    const float* __restrict__ W, int ldw, int N,
    float* __restrict__ O1, const float* __restrict__ bias)
{
  constexpr int AROWS = MT*16, BROWS = NT*16;
  constexpr int WM = MT/4;
  constexpr int CA = MT/4, CB = NT/4;
  __shared__ __align__(16) short As[AROWS*40];
  __shared__ __align__(16) short Bs[BROWS*40];
  const int tid = threadIdx.x;
  const int lane = tid & 63, w = tid >> 6;
  const int ml = lane & 15, quad = lane >> 4;
  const int mb = blockIdx.y * AROWS, nb = blockIdx.x * BROWS;

  float4v acc[WM][NT];
  #pragma unroll
  for (int im = 0; im < WM; ++im)
    #pragma unroll
    for (int j = 0; j < NT; ++j)
      acc[im][j] = (float4v){0.f, 0.f, 0.f, 0.f};

  for (int kt = 0; kt < KT; ++kt){
    const int k0 = kt * 32;
    float4 a0[CA], a1[CA], b0[CB], b1[CB];
    #pragma unroll
    for (int c = 0; c < CA; ++c){
      int id = tid + c*256, row = id >> 2, q = id & 3;
      if (K16 && q >= 2){
        a0[c] = make_float4(0,0,0,0); a1[c] = make_float4(0,0,0,0);
      } else {
        const float* p = A + (size_t)(mb+row)*lda + k0 + q*8;
        a0[c] = *(const float4*)p; a1[c] = *(const float4*)(p+4);
      }
    }
    #pragma unroll
    for (int c = 0; c < CB; ++c){
      int id = tid + c*256, row = id >> 2, q = id & 3;
      bool ok = !(K16 && q >= 2) && !(MODE == 1 && (nb + row) >= N);
      if (ok){
        const float* p = W + (size_t)(nb+row)*ldw + k0 + q*8;
        b0[c] = *(const float4*)p; b1[c] = *(const float4*)(p+4);
      } else {
        b0[c] = make_float4(0,0,0,0); b1[c] = make_float4(0,0,0,0);
      }
    }
    __syncthreads();
    #pragma unroll
    for (int c = 0; c < CA; ++c){
      int id = tid + c*256, row = id >> 2, q = id & 3;
      short8 s;
      s[0]=f2bf(a0[c].x); s[1]=f2bf(a0[c].y); s[2]=f2bf(a0[c].z); s[3]=f2bf(a0[c].w);
      s[4]=f2bf(a1[c].x); s[5]=f2bf(a1[c].y); s[6]=f2bf(a1[c].z); s[7]=f2bf(a1[c].w);
      *(short8*)&As[row*40 + q*8] = s;
    }
    #pragma unroll
    for (int c = 0; c < CB; ++c){
      int id = tid + c*256, row = id >> 2, q = id & 3;
      short8 s;
      s[0]=f2bf(b0[c].x); s[1]=f2bf(b0[c].y); s[2]=f2bf(b0[c].z); s[3]=f2bf(b0[c].w);
      s[4]=f2bf(b1[c].x); s[5]=f2bf(b1[c].y); s[6]=f2bf(b1[c].z); s[7]=f2bf(b1[c].w);
      *(short8*)&Bs[row*40 + q*8] = s;
    }
    __syncthreads();

    short8 af[WM];
    #pragma unroll
    for (int im = 0; im < WM; ++im)
      af[im] = *(const short8*)&As[((w*WM+im)*16 + ml)*40 + quad*8];
    #pragma unroll
    for (int j = 0; j < NT; ++j){
      short8 bf = *(const short8*)&Bs[(j*16 + ml)*40 + quad*8];
      #pragma unroll
      for (int im = 0; im < WM; ++im)
        acc[im][j] = __builtin_amdgcn_mfma_f32_16x16x32_bf16(af[im], bf, acc[im][j], 0, 0, 0);
    }
  }

  #pragma unroll
  for (int im = 0; im < WM; ++im){
    const int mt0 = mb + (w*WM + im)*16 + quad*4;
    #pragma unroll
    for (int j = 0; j < NT; ++j){
      const int ng = nb + j*16 + ml;
      #pragma unroll
      for (int r = 0; r < 4; ++r){
        int mg = mt0 + r;
        float v = acc[im][j][r];
        if (MODE == 1){
          if (ng < N) O1[(size_t)mg*48 + ng] = v;
        } else { // MODE 5: dtT[d=mg][r=ng]
          O1[(size_t)mg*16384 + ng] = softplus_f(v + bias[mg]);
        }
      }
    }
  }
}

// ---------------- Causal conv (w=4) + SiLU, tiled; emits xc (row-major) + uT (d-major) ----------------
__global__ __launch_bounds__(256) void conv_tile(const float* __restrict__ xin,
    const float* __restrict__ w, const float* __restrict__ cb,
    float* __restrict__ xc, float* __restrict__ uT)
{
  __shared__ float tile[67][65];   // +1 pad: conflict-free column reads
  const int r0 = blockIdx.x * 64;  // 256 r-tiles
  const int d0 = blockIdx.y * 64;  // 8 d-tiles
  const int tid = threadIdx.x;
  const bool halo_ok = (r0 & 4095) != 0;   // batch boundary: zero halo
  for (int e = tid; e < 67*64; e += 256){
    int rr = e >> 6, dd = e & 63;
    float v = 0.f;
    if (rr >= 3 || halo_ok) v = xin[(size_t)(r0 + rr - 3)*512 + d0 + dd];
    tile[rr][dd] = v;
  }
  __syncthreads();
  // xc: r-major mapping (coalesced along d)
  #pragma unroll 4
  for (int i = 0; i < 16; ++i){
    int e = tid + i*256; int r = e >> 6, dd = e & 63;
    int d = d0 + dd;
    float acc = cb[d];
    #pragma unroll
    for (int j = 0; j < 4; ++j) acc = fmaf(w[d*4 + j], tile[r + j][dd], acc);
    xc[(size_t)(r0 + r)*512 + d] = silu_f(acc);
  }
  // uT: d-major mapping (coalesced along r)
  #pragma unroll 4
  for (int i = 0; i < 16; ++i){
    int e = tid + i*256; int dd = e >> 6, r = e & 63;
    int d = d0 + dd;
    float acc = cb[d];
    #pragma unroll
    for (int j = 0; j < 4; ++j) acc = fmaf(w[d*4 + j], tile[r + j][dd], acc);
    uT[(size_t)d*16384 + r0 + r] = silu_f(acc);
  }
}

// ---------------- Chunk-parallel selective scan ----------------
// Wave: 4 channels x 16 states; dt/u loaded coalesced from transposed buffers,
// broadcast per-step via shfl.
__global__ __launch_bounds__(256) void scan_phaseA(
    const float* __restrict__ uT, const float* __restrict__ dtT,
    const float* __restrict__ dbl, const float* __restrict__ A_log,
    float* __restrict__ hstate,   // (NCHUNK, 32768)
    float* __restrict__ dtsum)    // (NCHUNK, 2048)
{
  int wg = (blockIdx.x * 256 + threadIdx.x) >> 6;
  int lane = threadIdx.x & 63;
  int b = wg >> 13;
  int chunk = (wg >> 7) & (NCHUNK - 1);
  int dg = wg & 127;
  int d = dg * 4 + (lane >> 4);
  int n = lane & 15;
  int base = lane & 48;
  float Acoef = -__expf(A_log[d*16 + n]);
  float h = 0.f;
  int r0 = b * LSEQ + chunk * CHUNK;
  size_t tb = (size_t)d * 16384 + r0;
  float dt_l[4], u_l[4];
  #pragma unroll
  for (int bt = 0; bt < 4; ++bt){
    dt_l[bt] = dtT[tb + bt*16 + n];
    u_l[bt]  = uT [tb + bt*16 + n];
  }
  for (int bt = 0; bt < 4; ++bt){
    int row = r0 + bt*16;
    #pragma unroll
    for (int t = 0; t < 16; ++t){
      float dtv = __shfl(dt_l[bt], base + t);
      float uv  = __shfl(u_l[bt],  base + t);
      float Bv  = dbl[(size_t)(row + t)*48 + 16 + n];
      h = fmaf(h, __expf(dtv * Acoef), dtv * uv * Bv);
    }
  }
  hstate[(size_t)chunk*32768 + (size_t)(b*512 + d)*16 + n] = h;
  float dacc = dt_l[0] + dt_l[1] + dt_l[2] + dt_l[3];
  dacc += __shfl_xor(dacc, 1);
  dacc += __shfl_xor(dacc, 2);
  dacc += __shfl_xor(dacc, 4);
  dacc += __shfl_xor(dacc, 8);
  if (n == 0) dtsum[chunk*2048 + b*512 + d] = dacc;
}

// Combine: sequential over chunks per (b,d,n); overwrite hstate with h_init.
__global__ __launch_bounds__(256) void scan_combine(
    const float* __restrict__ A_log,
    float* __restrict__ hstate, const float* __restrict__ dtsum)
{
  int idx = blockIdx.x * 256 + threadIdx.x;  // 0..32767
  int n = idx & 15, dd = idx >> 4;           // dd = b*512+d
  int d = dd & 511;
  float Acoef = -__expf(A_log[d*16 + n]);
  float H = 0.f;
  for (int c = 0; c < NCHUNK; ++c){
    float S = dtsum[c*2048 + dd];
    float tmp = hstate[(size_t)c*32768 + idx];
    hstate[(size_t)c*32768 + idx] = H;       // h_init for chunk c
    H = fmaf(H, __expf(Acoef * S), tmp);
  }
}

// Phase B: rescan with true h_init; batched 16-value butterfly reduce; y -> bf16.
__global__ __launch_bounds__(256) void scan_phaseB(
    const float* __restrict__ uT, const float* __restrict__ dtT,
    const float* __restrict__ dbl, const float* __restrict__ A_log,
    const float* __restrict__ Dp, const float* __restrict__ z,
    const float* __restrict__ hstate,
    short* __restrict__ y)
{
  int wg = (blockIdx.x * 256 + threadIdx.x) >> 6;
  int lane = threadIdx.x & 63;
  int b = wg >> 13;
  int chunk = (wg >> 7) & (NCHUNK - 1);
  int dg = wg & 127;
  int d = dg * 4 + (lane >> 4);
  int n = lane & 15;
  int base = lane & 48;
  float Acoef = -__expf(A_log[d*16 + n]);
  float Dv0 = (n == 0) ? Dp[d] : 0.f;
  float h = hstate[(size_t)chunk*32768 + (size_t)(b*512 + d)*16 + n];
  int r0 = b * LSEQ + chunk * CHUNK;
  size_t tb = (size_t)d * 16384 + r0;
  const int tt_out = ((n&1)<<3) | ((n&2)<<1) | ((n&4)>>1) | ((n&8)>>3);
  float dt_l[4], u_l[4];
  #pragma unroll
  for (int bt = 0; bt < 4; ++bt){
    dt_l[bt] = dtT[tb + bt*16 + n];
    u_l[bt]  = uT [tb + bt*16 + n];
  }

  for (int bt = 0; bt < 4; ++bt){
    int row = r0 + bt*16;
    float py[16];
    #pragma unroll
    for (int t = 0; t < 16; ++t){
      float dtv = __shfl(dt_l[bt], base + t);
      float uv  = __shfl(u_l[bt],  base + t);
      size_t rr = (size_t)(row + t)*48;
      float Bv = dbl[rr + 16 + n];
      float Cv = dbl[rr + 32 + n];
      h = fmaf(h, __expf(dtv * Acoef), dtv * uv * Bv);
      py[t] = fmaf(uv, Dv0, h * Cv);
    }
    #pragma unroll
    for (int i = 0; i < 8; ++i){
      float lo = py[i], hi = py[i+8];
      float recv = __shfl_xor((n & 1) ? lo : hi, 1);
      py[i] = ((n & 1) ? hi : lo) + recv;
    }
    #pragma unroll
    for (int i = 0; i < 4; ++i){
      float lo = py[i], hi = py[i+4];
      float recv = __shfl_xor((n & 2) ? lo : hi, 2);
      py[i] = ((n & 2) ? hi : lo) + recv;
    }
    #pragma unroll
    for (int i = 0; i < 2; ++i){
      float lo = py[i], hi = py[i+2];
      float recv = __shfl_xor((n & 4) ? lo : hi, 4);
      py[i] = ((n & 4) ? hi : lo) + recv;
    }
    {
      float lo = py[0], hi = py[1];
      float recv = __shfl_xor((n & 8) ? lo : hi, 8);
      py[0] = ((n & 8) ? hi : lo) + recv;
    }
    int re = row + tt_out;
    float zv = z[(size_t)re*512 + d];
    y[(size_t)re*512 + d] = f2bf(py[0] * silu_f(zv));
  }
}

extern "C" void kernel_launch(void* const* d_in, const int* in_sizes, int n_in,
                              void* d_out, int out_size, void* d_ws, size_t ws_size,
                              hipStream_t stream)
{
  const float* x          = (const float*)d_in[0];   // (4,256,64,64)
  const float* norm_w     = (const float*)d_in[1];
  const float* norm_b     = (const float*)d_in[2];
  const float* in_proj_w  = (const float*)d_in[3];   // (1024,256)
  const float* conv_w     = (const float*)d_in[4];   // (512,1,4)
  const float* conv_b     = (const float*)d_in[5];
  const float* x_proj_w   = (const float*)d_in[6];   // (48,512)
  const float* dt_proj_w  = (const float*)d_in[7];   // (512,16)
  const float* dt_proj_b  = (const float*)d_in[8];
  const float* A_log      = (const float*)d_in[9];   // (512,16)
  const float* D_ssm      = (const float*)d_in[10];
  const float* out_proj_w = (const float*)d_in[11];  // (256,512)
  const float* proj_w     = (const float*)d_in[12];  // (256,256)
  const float* proj_b     = (const float*)d_in[13];
  const float* skip_scale = (const float*)d_in[14];
  float* out = (float*)d_out;

  char* ws = (char*)d_ws;
  // [0,8): xn_bf16, later hstate. [8,8.5): dtsum. [8.5,10): bf16 weights.
  // [16,48): xin f32, later dtT. [48,80): z f32. [80,96): xc f32 -> y bf16.
  // [96,112): xc tail -> xm bf16. [112,144): uT. [144,147): dbl.
  short* xnb    = (short*)(ws);
  float* hstate = (float*)(ws);
  float* dtsum  = (float*)(ws + ((size_t)8 << 20));
  short* in_wb  = (short*)(ws + ((size_t)8 << 20) + (512 << 10));
  short* out_wb = (short*)(ws + ((size_t)9 << 20));
  short* proj_wb= (short*)(ws + ((size_t)9 << 20) + (256 << 10));
  float* xin    = (float*)(ws + ((size_t)16 << 20));
  float* dtT    = (float*)(ws + ((size_t)16 << 20));
  float* zb     = (float*)(ws + ((size_t)48 << 20));
  float* xc     = (float*)(ws + ((size_t)80 << 20));
  short* yb     = (short*)(ws + ((size_t)80 << 20));
  short* xmb    = (short*)(ws + ((size_t)96 << 20));
  float* uT     = (float*)(ws + ((size_t)112 << 20));
  float* dbl    = (float*)(ws + ((size_t)144 << 20));

  // 0) weight conversion
  convert_w<<<1024, 256, 0, stream>>>(in_proj_w, out_proj_w, proj_w,
                                      in_wb, out_wb, proj_wb);

  // 1) LayerNorm -> bf16
  ln_kernel<<<NROWS, 256, 0, stream>>>(x, norm_w, norm_b, xnb);

  // 2) in_proj: (16384,1024,256) bf16 MFMA, split into xin / z (f32)
  gemm_bf16<0, 8, 8, 8><<<dim3(8, 128), 256, 0, stream>>>(
      xnb, 256, in_wb, 256, xin, zb, nullptr, nullptr, nullptr, nullptr);

  // 3) causal conv + SiLU -> xc (row-major) + uT (d-major)
  conv_tile<<<dim3(256, 8), 256, 0, stream>>>(xin, conv_w, conv_b, xc, uT);

  // 4) x_proj: (16384,48,512) f32-staged
  gemm_mfma<1, 4, 4, 16, false><<<dim3(1, 256), 256, 0, stream>>>(
      xc, 512, x_proj_w, 512, 48, dbl, nullptr);

  // 5) dt_proj swapped: dtT[d][r] = softplus(dt_w @ dbl[:, :16]^T + b)
  gemm_mfma<5, 4, 8, 1, true><<<dim3(128, 8), 256, 0, stream>>>(
      dt_proj_w, 16, dbl, 48, 16384, dtT, dt_proj_b);

  // 6) chunk-parallel selective scan
  scan_phaseA<<<8192, 256, 0, stream>>>(uT, dtT, dbl, A_log, hstate, dtsum);
  scan_combine<<<128, 256, 0, stream>>>(A_log, hstate, dtsum);
  scan_phaseB<<<8192, 256, 0, stream>>>(uT, dtT, dbl, A_log, D_ssm, zb, hstate, yb);

  // 7) out_proj + skip -> xm bf16: (16384,256,512)
  gemm_bf16<2, 8, 8, 16><<<dim3(2, 128), 256, 0, stream>>>(
      yb, 512, out_wb, 512, nullptr, nullptr, xmb, nullptr, x, skip_scale);

  // 8) final proj (operand-swapped) -> out f32 (B,C,L)
  gemm_bf16<3, 8, 8, 8><<<dim3(128, 2), 256, 0, stream>>>(
      proj_wb, 256, xmb, 256, out, nullptr, nullptr, proj_b, nullptr, nullptr);
}

// Round 6
// 361.693 us; speedup vs baseline: 9.2652x; 1.0278x over previous
//
#include <hip/hip_runtime.h>
#include <math.h>

// Problem constants
#define LSEQ   4096       // H*W
#define BSZ    4
#define DMODEL 256
#define DINNER 512
#define NROWS  16384      // B*L
#define CHUNK  64
#define NCHUNK 64         // LSEQ / CHUNK

typedef __attribute__((ext_vector_type(8))) short short8;
typedef __attribute__((ext_vector_type(4))) float float4v;

__device__ __forceinline__ float silu_f(float v){ return v / (1.f + __expf(-v)); }
__device__ __forceinline__ float softplus_f(float v){
  return v > 0.f ? v + log1pf(__expf(-v)) : log1pf(__expf(v));
}
__device__ __forceinline__ short f2bf(float x){   // RNE f32 -> bf16 bits
  unsigned int u = __float_as_uint(x);
  unsigned int r = (u + 0x7fffu + ((u >> 16) & 1u)) >> 16;
  return (short)r;
}
__device__ __forceinline__ float bf2f(short s){
  return __uint_as_float(((unsigned int)(unsigned short)s) << 16);
}

// ---------------- weight pre-convert (f32 -> bf16) ----------------
__global__ __launch_bounds__(256) void convert_w(
    const float* __restrict__ a, const float* __restrict__ b, const float* __restrict__ c,
    short* __restrict__ oa, short* __restrict__ ob, short* __restrict__ oc)
{
  int i = blockIdx.x * 256 + threadIdx.x;
  if (i < 262144) oa[i] = f2bf(a[i]);   // in_proj_w 1024*256
  if (i < 24576)  ob[i] = f2bf(b[i]);   // x_proj_w 48*512
  if (i < 65536)  oc[i] = f2bf(c[i]);   // proj_w 256*256
}

// ---------------- fused weight: Wf = proj_w @ out_proj_w  (256 x 512) ----------------
__global__ __launch_bounds__(256) void fuse_w(
    const float* __restrict__ pw, const float* __restrict__ ow, short* __restrict__ wf)
{
  int idx = blockIdx.x * 256 + threadIdx.x;   // 131072
  int m = idx >> 9, c = idx & 511;
  float acc = 0.f;
  #pragma unroll 4
  for (int k = 0; k < 256; ++k) acc = fmaf(pw[m*256 + k], ow[k*512 + c], acc);
  wf[idx] = f2bf(acc);
}

// ---------------- LayerNorm, LDS-transposed tiles -> bf16 ----------------
__global__ __launch_bounds__(256) void ln_tile(const float* __restrict__ x,
    const float* __restrict__ w, const float* __restrict__ bias,
    short* __restrict__ xnb)
{
  __shared__ float tile[32*257];
  const int blk = blockIdx.x;        // 512 blocks
  const int b = blk >> 7;
  const int l0 = (blk & 127) << 5;   // 32 rows of l per block
  const int tid = threadIdx.x;
  const int lq = tid & 31, ch = tid >> 5;   // 8 c-groups
  #pragma unroll 8
  for (int i = 0; i < 32; ++i){
    int c = i*8 + ch;
    tile[lq*257 + c] = x[((size_t)(b*DMODEL + c) << 12) + l0 + lq];
  }
  __syncthreads();
  const int wv = tid >> 6, lane = tid & 63;
  float wc[4], bc[4];
  #pragma unroll
  for (int q = 0; q < 4; ++q){ wc[q] = w[q*64 + lane]; bc[q] = bias[q*64 + lane]; }
  for (int j = 0; j < 8; ++j){
    int row = wv*8 + j;
    float s1 = 0.f, s2 = 0.f, vals[4];
    #pragma unroll
    for (int q = 0; q < 4; ++q){
      float v = tile[row*257 + q*64 + lane];
      vals[q] = v; s1 += v; s2 += v*v;
    }
    #pragma unroll
    for (int o = 1; o < 64; o <<= 1){ s1 += __shfl_xor(s1, o); s2 += __shfl_xor(s2, o); }
    float mu = s1 * (1.f/256.f);
    float var = s2 * (1.f/256.f) - mu*mu;
    float rs = rsqrtf(var + 1e-5f);
    size_t ro = (size_t)(b*LSEQ + l0 + row) * 256;
    #pragma unroll
    for (int q = 0; q < 4; ++q)
      xnb[ro + q*64 + lane] = f2bf((vals[q] - mu) * rs * wc[q] + bc[q]);
  }
}

// ---------------- bf16-input MFMA GEMM: D = A @ W^T ----------------
// MODE 0: split bf16 write at col 512 (in_proj -> xin, z)
// MODE 1: f32 stride-48 write, guard ng<N=48 (x_proj)
template<int MODE, int MT, int NT, int KT>
__global__ __launch_bounds__(256) void gemm_bf16(
    const short* __restrict__ A, int lda,
    const short* __restrict__ W, int ldw,
    short* __restrict__ Ob1, short* __restrict__ Ob2, float* __restrict__ Of)
{
  constexpr int AROWS = MT*16, BROWS = NT*16;
  constexpr int WM = MT/4;
  constexpr int CA = MT/4, CB = NT/4;
  __shared__ __align__(16) short As[AROWS*40];
  __shared__ __align__(16) short Bs[BROWS*40];
  const int tid = threadIdx.x;
  const int lane = tid & 63, wv = tid >> 6;
  const int ml = lane & 15, quad = lane >> 4;
  const int mb = blockIdx.y * AROWS, nb = blockIdx.x * BROWS;

  float4v acc[WM][NT];
  #pragma unroll
  for (int im = 0; im < WM; ++im)
    #pragma unroll
    for (int j = 0; j < NT; ++j)
      acc[im][j] = (float4v){0.f, 0.f, 0.f, 0.f};

  for (int kt = 0; kt < KT; ++kt){
    const int k0 = kt * 32;
    short8 av[CA], bv[CB];
    #pragma unroll
    for (int c = 0; c < CA; ++c){
      int id = tid + c*256, row = id >> 2, q = id & 3;
      av[c] = *(const short8*)(A + (size_t)(mb+row)*lda + k0 + q*8);
    }
    #pragma unroll
    for (int c = 0; c < CB; ++c){
      int id = tid + c*256, row = id >> 2, q = id & 3;
      if (MODE == 1 && (nb + row) >= 48){
        short8 zz = {0,0,0,0,0,0,0,0};
        bv[c] = zz;
      } else {
        bv[c] = *(const short8*)(W + (size_t)(nb+row)*ldw + k0 + q*8);
      }
    }
    __syncthreads();
    #pragma unroll
    for (int c = 0; c < CA; ++c){
      int id = tid + c*256, row = id >> 2, q = id & 3;
      *(short8*)&As[row*40 + q*8] = av[c];
    }
    #pragma unroll
    for (int c = 0; c < CB; ++c){
      int id = tid + c*256, row = id >> 2, q = id & 3;
      *(short8*)&Bs[row*40 + q*8] = bv[c];
    }
    __syncthreads();

    short8 af[WM];
    #pragma unroll
    for (int im = 0; im < WM; ++im)
      af[im] = *(const short8*)&As[((wv*WM+im)*16 + ml)*40 + quad*8];
    #pragma unroll
    for (int j = 0; j < NT; ++j){
      short8 bf = *(const short8*)&Bs[(j*16 + ml)*40 + quad*8];
      #pragma unroll
      for (int im = 0; im < WM; ++im)
        acc[im][j] = __builtin_amdgcn_mfma_f32_16x16x32_bf16(af[im], bf, acc[im][j], 0, 0, 0);
    }
  }

  #pragma unroll
  for (int im = 0; im < WM; ++im){
    const int mt0 = mb + (wv*WM + im)*16 + quad*4;
    #pragma unroll
    for (int j = 0; j < NT; ++j){
      const int ng = nb + j*16 + ml;
      #pragma unroll
      for (int r = 0; r < 4; ++r){
        int mg = mt0 + r;
        float v = acc[im][j][r];
        if (MODE == 0){
          if (ng < DINNER) Ob1[(size_t)mg*DINNER + ng] = f2bf(v);
          else             Ob2[(size_t)mg*DINNER + (ng - DINNER)] = f2bf(v);
        } else { // MODE 1
          if (ng < 48) Of[(size_t)mg*48 + ng] = v;
        }
      }
    }
  }
}

// ---------------- f32-input MFMA GEMM, dt_proj (operand-swapped) ----------------
// dtT[d][r] = softplus((dt_proj_w @ dbl[:, :16]^T)[d][r] + bias[d])
template<int MT, int NT>
__global__ __launch_bounds__(256) void gemm_dt(
    const float* __restrict__ A, int lda,      // dt_proj_w (512,16)
    const float* __restrict__ W, int ldw,      // dbl (16384,48)
    float* __restrict__ O1, const float* __restrict__ bias)
{
  constexpr int AROWS = MT*16, BROWS = NT*16;
  constexpr int WM = MT/4;
  constexpr int CA = MT/4, CB = NT/4;
  __shared__ __align__(16) short As[AROWS*40];
  __shared__ __align__(16) short Bs[BROWS*40];
  const int tid = threadIdx.x;
  const int lane = tid & 63, wv = tid >> 6;
  const int ml = lane & 15, quad = lane >> 4;
  const int mb = blockIdx.y * AROWS, nb = blockIdx.x * BROWS;

  float4v acc[WM][NT];
  #pragma unroll
  for (int im = 0; im < WM; ++im)
    #pragma unroll
    for (int j = 0; j < NT; ++j)
      acc[im][j] = (float4v){0.f, 0.f, 0.f, 0.f};

  {
    float4 a0[CA], a1[CA], b0[CB], b1[CB];
    #pragma unroll
    for (int c = 0; c < CA; ++c){
      int id = tid + c*256, row = id >> 2, q = id & 3;
      if (q >= 2){ a0[c] = make_float4(0,0,0,0); a1[c] = make_float4(0,0,0,0); }
      else {
        const float* p = A + (size_t)(mb+row)*lda + q*8;
        a0[c] = *(const float4*)p; a1[c] = *(const float4*)(p+4);
      }
    }
    #pragma unroll
    for (int c = 0; c < CB; ++c){
      int id = tid + c*256, row = id >> 2, q = id & 3;
      if (q >= 2){ b0[c] = make_float4(0,0,0,0); b1[c] = make_float4(0,0,0,0); }
      else {
        const float* p = W + (size_t)(nb+row)*ldw + q*8;
        b0[c] = *(const float4*)p; b1[c] = *(const float4*)(p+4);
      }
    }
    #pragma unroll
    for (int c = 0; c < CA; ++c){
      int id = tid + c*256, row = id >> 2, q = id & 3;
      short8 s;
      s[0]=f2bf(a0[c].x); s[1]=f2bf(a0[c].y); s[2]=f2bf(a0[c].z); s[3]=f2bf(a0[c].w);
      s[4]=f2bf(a1[c].x); s[5]=f2bf(a1[c].y); s[6]=f2bf(a1[c].z); s[7]=f2bf(a1[c].w);
      *(short8*)&As[row*40 + q*8] = s;
    }
    #pragma unroll
    for (int c = 0; c < CB; ++c){
      int id = tid + c*256, row = id >> 2, q = id & 3;
      short8 s;
      s[0]=f2bf(b0[c].x); s[1]=f2bf(b0[c].y); s[2]=f2bf(b0[c].z); s[3]=f2bf(b0[c].w);
      s[4]=f2bf(b1[c].x); s[5]=f2bf(b1[c].y); s[6]=f2bf(b1[c].z); s[7]=f2bf(b1[c].w);
      *(short8*)&Bs[row*40 + q*8] = s;
    }
    __syncthreads();
    short8 af[WM];
    #pragma unroll
    for (int im = 0; im < WM; ++im)
      af[im] = *(const short8*)&As[((wv*WM+im)*16 + ml)*40 + quad*8];
    #pragma unroll
    for (int j = 0; j < NT; ++j){
      short8 bf = *(const short8*)&Bs[(j*16 + ml)*40 + quad*8];
      #pragma unroll
      for (int im = 0; im < WM; ++im)
        acc[im][j] = __builtin_amdgcn_mfma_f32_16x16x32_bf16(af[im], bf, acc[im][j], 0, 0, 0);
    }
  }

  #pragma unroll
  for (int im = 0; im < WM; ++im){
    const int mt0 = mb + (wv*WM + im)*16 + quad*4;
    #pragma unroll
    for (int j = 0; j < NT; ++j){
      const int ng = nb + j*16 + ml;
      #pragma unroll
      for (int r = 0; r < 4; ++r){
        int mg = mt0 + r;
        O1[(size_t)mg*16384 + ng] = softplus_f(acc[im][j][r] + bias[mg]);
      }
    }
  }
}

// ---------------- Fused final GEMM ----------------
// out[b,mg,l] = sum_k Wf[mg,k]*y[r,k] + s*sum_c proj_w[mg,c]*x[b,c,l] + bias[mg]
__global__ __launch_bounds__(256) void gemm_final(
    const short* __restrict__ Wf, const short* __restrict__ Pw,
    const short* __restrict__ Y, const float* __restrict__ x,
    const float* __restrict__ sscale, const float* __restrict__ bias,
    float* __restrict__ out)
{
  __shared__ __align__(16) short As[128*40];
  __shared__ __align__(16) short Bs[128*40];
  const int tid = threadIdx.x;
  const int lane = tid & 63, wv = tid >> 6;
  const int ml = lane & 15, quad = lane >> 4;
  const int mb = blockIdx.y * 128;
  const int r0 = blockIdx.x * 128;
  const int b = r0 >> 12, l0 = r0 & 4095;
  const float ss = sscale[0];

  float4v acc[2][8];
  #pragma unroll
  for (int im = 0; im < 2; ++im)
    #pragma unroll
    for (int j = 0; j < 8; ++j)
      acc[im][j] = (float4v){0.f, 0.f, 0.f, 0.f};

  for (int kt = 0; kt < 24; ++kt){
    const bool xpart = kt >= 16;
    short8 av[2];
    #pragma unroll
    for (int c = 0; c < 2; ++c){
      int id = tid + c*256, row = id >> 2, q = id & 3;
      av[c] = xpart
        ? *(const short8*)(Pw + (size_t)(mb+row)*256 + (kt-16)*32 + q*8)
        : *(const short8*)(Wf + (size_t)(mb+row)*512 + kt*32 + q*8);
    }
    short8 bv[2], bx0, bx1;
    if (!xpart){
      #pragma unroll
      for (int c = 0; c < 2; ++c){
        int id = tid + c*256, row = id >> 2, q = id & 3;
        bv[c] = *(const short8*)(Y + (size_t)(r0+row)*512 + kt*32 + q*8);
      }
    } else {
      int row = tid & 127, kc = tid >> 7;
      int cbase = (kt-16)*32 + kc*16;
      #pragma unroll
      for (int i = 0; i < 8; ++i)
        bx0[i] = f2bf(ss * x[((size_t)(b*DMODEL + cbase + i) << 12) + l0 + row]);
      #pragma unroll
      for (int i = 0; i < 8; ++i)
        bx1[i] = f2bf(ss * x[((size_t)(b*DMODEL + cbase + 8 + i) << 12) + l0 + row]);
    }
    __syncthreads();
    #pragma unroll
    for (int c = 0; c < 2; ++c){
      int id = tid + c*256, row = id >> 2, q = id & 3;
      *(short8*)&As[row*40 + q*8] = av[c];
    }
    if (!xpart){
      #pragma unroll
      for (int c = 0; c < 2; ++c){
        int id = tid + c*256, row = id >> 2, q = id & 3;
        *(short8*)&Bs[row*40 + q*8] = bv[c];
      }
    } else {
      int row = tid & 127, kc = tid >> 7;
      *(short8*)&Bs[row*40 + kc*16]     = bx0;
      *(short8*)&Bs[row*40 + kc*16 + 8] = bx1;
    }
    __syncthreads();

    short8 af[2];
    #pragma unroll
    for (int im = 0; im < 2; ++im)
      af[im] = *(const short8*)&As[((wv*2+im)*16 + ml)*40 + quad*8];
    #pragma unroll
    for (int j = 0; j < 8; ++j){
      short8 bf = *(const short8*)&Bs[(j*16 + ml)*40 + quad*8];
      #pragma unroll
      for (int im = 0; im < 2; ++im)
        acc[im][j] = __builtin_amdgcn_mfma_f32_16x16x32_bf16(af[im], bf, acc[im][j], 0, 0, 0);
    }
  }

  #pragma unroll
  for (int im = 0; im < 2; ++im){
    const int mt0 = mb + (wv*2 + im)*16 + quad*4;
    #pragma unroll
    for (int j = 0; j < 8; ++j){
      const int l = l0 + j*16 + ml;
      #pragma unroll
      for (int r = 0; r < 4; ++r){
        int mg = mt0 + r;
        out[((size_t)(b*DMODEL + mg) << 12) + l] = acc[im][j][r] + bias[mg];
      }
    }
  }
}

// ---------------- Causal conv (w=4) + SiLU; bf16 in/out ----------------
__global__ __launch_bounds__(256) void conv_tile(const short* __restrict__ xin,
    const float* __restrict__ w, const float* __restrict__ cb,
    short* __restrict__ xcb, short* __restrict__ uTb)
{
  __shared__ float tile[67][65];
  const int r0 = blockIdx.x * 64;
  const int d0 = blockIdx.y * 64;
  const int tid = threadIdx.x;
  const bool halo_ok = (r0 & 4095) != 0;
  for (int e = tid; e < 67*64; e += 256){
    int rr = e >> 6, dd = e & 63;
    float v = 0.f;
    if (rr >= 3 || halo_ok) v = bf2f(xin[(size_t)(r0 + rr - 3)*512 + d0 + dd]);
    tile[rr][dd] = v;
  }
  __syncthreads();
  #pragma unroll 4
  for (int i = 0; i < 16; ++i){
    int e = tid + i*256; int r = e >> 6, dd = e & 63;
    int d = d0 + dd;
    float acc = cb[d];
    #pragma unroll
    for (int j = 0; j < 4; ++j) acc = fmaf(w[d*4 + j], tile[r + j][dd], acc);
    xcb[(size_t)(r0 + r)*512 + d] = f2bf(silu_f(acc));
  }
  #pragma unroll 4
  for (int i = 0; i < 16; ++i){
    int e = tid + i*256; int dd = e >> 6, r = e & 63;
    int d = d0 + dd;
    float acc = cb[d];
    #pragma unroll
    for (int j = 0; j < 4; ++j) acc = fmaf(w[d*4 + j], tile[r + j][dd], acc);
    uTb[(size_t)d*16384 + r0 + r] = f2bf(silu_f(acc));
  }
}

// ---------------- Chunk-parallel selective scan ----------------
__global__ __launch_bounds__(256) void scan_phaseA(
    const short* __restrict__ uT, const float* __restrict__ dtT,
    const float* __restrict__ dbl, const float* __restrict__ A_log,
    float* __restrict__ hstate, float* __restrict__ dtsum)
{
  int wg = (blockIdx.x * 256 + threadIdx.x) >> 6;
  int lane = threadIdx.x & 63;
  int b = wg >> 13;
  int chunk = (wg >> 7) & (NCHUNK - 1);
  int dg = wg & 127;
  int d = dg * 4 + (lane >> 4);
  int n = lane & 15;
  int base = lane & 48;
  float Acoef = -__expf(A_log[d*16 + n]);
  float h = 0.f;
  int r0 = b * LSEQ + chunk * CHUNK;
  size_t tb = (size_t)d * 16384 + r0;
  float dt_l[4], u_l[4];
  #pragma unroll
  for (int bt = 0; bt < 4; ++bt){
    dt_l[bt] = dtT[tb + bt*16 + n];
    u_l[bt]  = bf2f(uT[tb + bt*16 + n]);
  }
  for (int bt = 0; bt < 4; ++bt){
    int row = r0 + bt*16;
    #pragma unroll
    for (int t = 0; t < 16; ++t){
      float dtv = __shfl(dt_l[bt], base + t);
      float uv  = __shfl(u_l[bt],  base + t);
      float Bv  = dbl[(size_t)(row + t)*48 + 16 + n];
      h = fmaf(h, __expf(dtv * Acoef), dtv * uv * Bv);
    }
  }
  hstate[(size_t)chunk*32768 + (size_t)(b*512 + d)*16 + n] = h;
  float dacc = dt_l[0] + dt_l[1] + dt_l[2] + dt_l[3];
  dacc += __shfl_xor(dacc, 1);
  dacc += __shfl_xor(dacc, 2);
  dacc += __shfl_xor(dacc, 4);
  dacc += __shfl_xor(dacc, 8);
  if (n == 0) dtsum[chunk*2048 + b*512 + d] = dacc;
}

__global__ __launch_bounds__(256) void scan_combine(
    const float* __restrict__ A_log,
    float* __restrict__ hstate, const float* __restrict__ dtsum)
{
  int idx = blockIdx.x * 256 + threadIdx.x;
  int n = idx & 15, dd = idx >> 4;
  int d = dd & 511;
  float Acoef = -__expf(A_log[d*16 + n]);
  float H = 0.f;
  for (int c = 0; c < NCHUNK; ++c){
    float S = dtsum[c*2048 + dd];
    float tmp = hstate[(size_t)c*32768 + idx];
    hstate[(size_t)c*32768 + idx] = H;
    H = fmaf(H, __expf(Acoef * S), tmp);
  }
}

__global__ __launch_bounds__(256) void scan_phaseB(
    const short* __restrict__ uT, const float* __restrict__ dtT,
    const float* __restrict__ dbl, const float* __restrict__ A_log,
    const float* __restrict__ Dp, const short* __restrict__ z,
    const float* __restrict__ hstate,
    short* __restrict__ y)
{
  int wg = (blockIdx.x * 256 + threadIdx.x) >> 6;
  int lane = threadIdx.x & 63;
  int b = wg >> 13;
  int chunk = (wg >> 7) & (NCHUNK - 1);
  int dg = wg & 127;
  int d = dg * 4 + (lane >> 4);
  int n = lane & 15;
  int base = lane & 48;
  float Acoef = -__expf(A_log[d*16 + n]);
  float Dv0 = (n == 0) ? Dp[d] : 0.f;
  float h = hstate[(size_t)chunk*32768 + (size_t)(b*512 + d)*16 + n];
  int r0 = b * LSEQ + chunk * CHUNK;
  size_t tb = (size_t)d * 16384 + r0;
  const int tt_out = ((n&1)<<3) | ((n&2)<<1) | ((n&4)>>1) | ((n&8)>>3);
  float dt_l[4], u_l[4];
  #pragma unroll
  for (int bt = 0; bt < 4; ++bt){
    dt_l[bt] = dtT[tb + bt*16 + n];
    u_l[bt]  = bf2f(uT[tb + bt*16 + n]);
  }

  for (int bt = 0; bt < 4; ++bt){
    int row = r0 + bt*16;
    float py[16];
    #pragma unroll
    for (int t = 0; t < 16; ++t){
      float dtv = __shfl(dt_l[bt], base + t);
      float uv  = __shfl(u_l[bt],  base + t);
      size_t rr = (size_t)(row + t)*48;
      float Bv = dbl[rr + 16 + n];
      float Cv = dbl[rr + 32 + n];
      h = fmaf(h, __expf(dtv * Acoef), dtv * uv * Bv);
      py[t] = fmaf(uv, Dv0, h * Cv);
    }
    #pragma unroll
    for (int i = 0; i < 8; ++i){
      float lo = py[i], hi = py[i+8];
      float recv = __shfl_xor((n & 1) ? lo : hi, 1);
      py[i] = ((n & 1) ? hi : lo) + recv;
    }
    #pragma unroll
    for (int i = 0; i < 4; ++i){
      float lo = py[i], hi = py[i+4];
      float recv = __shfl_xor((n & 2) ? lo : hi, 2);
      py[i] = ((n & 2) ? hi : lo) + recv;
    }
    #pragma unroll
    for (int i = 0; i < 2; ++i){
      float lo = py[i], hi = py[i+2];
      float recv = __shfl_xor((n & 4) ? lo : hi, 4);
      py[i] = ((n & 4) ? hi : lo) + recv;
    }
    {
      float lo = py[0], hi = py[1];
      float recv = __shfl_xor((n & 8) ? lo : hi, 8);
      py[0] = ((n & 8) ? hi : lo) + recv;
    }
    int re = row + tt_out;
    float zv = bf2f(z[(size_t)re*512 + d]);
    y[(size_t)re*512 + d] = f2bf(py[0] * silu_f(zv));
  }
}

extern "C" void kernel_launch(void* const* d_in, const int* in_sizes, int n_in,
                              void* d_out, int out_size, void* d_ws, size_t ws_size,
                              hipStream_t stream)
{
  const float* x          = (const float*)d_in[0];
  const float* norm_w     = (const float*)d_in[1];
  const float* norm_b     = (const float*)d_in[2];
  const float* in_proj_w  = (const float*)d_in[3];
  const float* conv_w     = (const float*)d_in[4];
  const float* conv_b     = (const float*)d_in[5];
  const float* x_proj_w   = (const float*)d_in[6];
  const float* dt_proj_w  = (const float*)d_in[7];
  const float* dt_proj_b  = (const float*)d_in[8];
  const float* A_log      = (const float*)d_in[9];
  const float* D_ssm      = (const float*)d_in[10];
  const float* out_proj_w = (const float*)d_in[11];
  const float* proj_w     = (const float*)d_in[12];
  const float* proj_b     = (const float*)d_in[13];
  const float* skip_scale = (const float*)d_in[14];
  float* out = (float*)d_out;

  char* ws = (char*)d_ws;
  // [0,8): xnb bf16, later hstate f32. [8,8.5): dtsum.
  // [9,10): bf16 weights. [16,32): xin bf16; [16,48): dtT f32 (after conv).
  // [48,64): z bf16. [64,80): xc bf16. [80,96): uT bf16. [96,112): y bf16.
  // [112,115): dbl f32.
  short* xnb    = (short*)(ws);
  float* hstate = (float*)(ws);
  float* dtsum  = (float*)(ws + ((size_t)8 << 20));
  short* in_wb  = (short*)(ws + ((size_t)9 << 20));
  short* xp_wb  = (short*)(ws + ((size_t)9 << 20) + (512 << 10));
  short* proj_wb= (short*)(ws + ((size_t)9 << 20) + (576 << 10));
  short* wf_b   = (short*)(ws + ((size_t)9 << 20) + (704 << 10));
  short* xinb   = (short*)(ws + ((size_t)16 << 20));
  float* dtT    = (float*)(ws + ((size_t)16 << 20));
  short* zb     = (short*)(ws + ((size_t)48 << 20));
  short* xcb    = (short*)(ws + ((size_t)64 << 20));
  short* uTb    = (short*)(ws + ((size_t)80 << 20));
  short* yb     = (short*)(ws + ((size_t)96 << 20));
  float* dbl    = (float*)(ws + ((size_t)112 << 20));

  // 0) weight converts + fused weight
  convert_w<<<1024, 256, 0, stream>>>(in_proj_w, x_proj_w, proj_w,
                                      in_wb, xp_wb, proj_wb);
  fuse_w<<<512, 256, 0, stream>>>(proj_w, out_proj_w, wf_b);

  // 1) LayerNorm -> bf16
  ln_tile<<<512, 256, 0, stream>>>(x, norm_w, norm_b, xnb);

  // 2) in_proj -> xin bf16, z bf16
  gemm_bf16<0, 8, 8, 8><<<dim3(8, 128), 256, 0, stream>>>(
      xnb, 256, in_wb, 256, xinb, zb, nullptr);

  // 3) causal conv + SiLU -> xc bf16 (row-major) + uT bf16 (d-major)
  conv_tile<<<dim3(256, 8), 256, 0, stream>>>(xinb, conv_w, conv_b, xcb, uTb);

  // 4) x_proj -> dbl f32 (16384 x 48)
  gemm_bf16<1, 4, 4, 16><<<dim3(1, 256), 256, 0, stream>>>(
      xcb, 512, xp_wb, 512, nullptr, nullptr, dbl);

  // 5) dt_proj swapped -> dtT f32 (512 x 16384)
  gemm_dt<4, 8><<<dim3(128, 8), 256, 0, stream>>>(
      dt_proj_w, 16, dbl, 48, dtT, dt_proj_b);

  // 6) chunk-parallel selective scan
  scan_phaseA<<<8192, 256, 0, stream>>>(uTb, dtT, dbl, A_log, hstate, dtsum);
  scan_combine<<<128, 256, 0, stream>>>(A_log, hstate, dtsum);
  scan_phaseB<<<8192, 256, 0, stream>>>(uTb, dtT, dbl, A_log, D_ssm, zb, hstate, yb);

  // 7) fused (out_proj @ proj) + skip + bias -> out (B,C,L)
  gemm_final<<<dim3(128, 2), 256, 0, stream>>>(
      wf_b, proj_wb, yb, x, skip_scale, proj_b, out);
}